// Round 1
// baseline (4822.473 us; speedup 1.0000x reference)
//
#include <hip/hip_runtime.h>
#include <math.h>

#define BATCH 8
#define CDIM 768
#define NTOK 1024
#define NH 12
#define HDIM 64
#define MROWS (BATCH * NTOK)   // 8192

// ---------------- transpose [B,C,N] -> [B,N,C] ----------------
__global__ void k_transpose_in(const float* __restrict__ dec, float* __restrict__ x) {
    __shared__ float tile[32][33];
    int b = blockIdx.z;
    int n0 = blockIdx.x * 32;
    int c0 = blockIdx.y * 32;
    int tx = threadIdx.x, ty = threadIdx.y;
#pragma unroll
    for (int r = 0; r < 4; ++r) {
        int c = c0 + ty + r * 8;
        tile[ty + r * 8][tx] = dec[((size_t)b * CDIM + c) * NTOK + n0 + tx];
    }
    __syncthreads();
#pragma unroll
    for (int r = 0; r < 4; ++r) {
        int n = n0 + ty + r * 8;
        x[((size_t)b * NTOK + n) * CDIM + c0 + tx] = tile[tx][ty + r * 8];
    }
}

// ---------------- QKV projection (gathered GEMM) ----------------
// x:[8192,768] @ per-head W -> q/k/v in [B,H,N,64]
__global__ __launch_bounds__(256) void k_qkv(
    const float* __restrict__ x,
    const float* __restrict__ wq, const float* __restrict__ bq,
    const float* __restrict__ wk, const float* __restrict__ bk,
    const float* __restrict__ wv, const float* __restrict__ bv,
    float* __restrict__ q, float* __restrict__ k_, float* __restrict__ v) {
    __shared__ float As[64][17];
    __shared__ float Bs[16][64];
    int t = threadIdx.x;
    int ty = t >> 4, tx = t & 15;
    int r0 = blockIdx.x * 64;
    int by = blockIdx.y;  // 0..35
    int sect = by / NH, h = by % NH;
    const float* W; const float* bias; float* out;
    if (sect == 0)      { W = wq; bias = bq; out = q; }
    else if (sect == 1) { W = wk; bias = bk; out = k_; }
    else                { W = wv; bias = bv; out = v; }
    const float* Wh = W + (size_t)h * CDIM * HDIM;  // [768][64]
    float acc[4][4] = {};
    int la_row = t >> 2, la_k = (t & 3) * 4;
    int lb_k = t >> 4, lb_n = (t & 15) * 4;
    for (int k0 = 0; k0 < CDIM; k0 += 16) {
        float4 av = *(const float4*)&x[(size_t)(r0 + la_row) * CDIM + k0 + la_k];
        As[la_row][la_k + 0] = av.x; As[la_row][la_k + 1] = av.y;
        As[la_row][la_k + 2] = av.z; As[la_row][la_k + 3] = av.w;
        float4 bv4 = *(const float4*)&Wh[(size_t)(k0 + lb_k) * HDIM + lb_n];
        *(float4*)&Bs[lb_k][lb_n] = bv4;
        __syncthreads();
#pragma unroll
        for (int kk = 0; kk < 16; ++kk) {
            float a[4];
#pragma unroll
            for (int ii = 0; ii < 4; ++ii) a[ii] = As[ty * 4 + ii][kk];
            float4 bb = *(const float4*)&Bs[kk][tx * 4];
            float bl[4] = {bb.x, bb.y, bb.z, bb.w};
#pragma unroll
            for (int ii = 0; ii < 4; ++ii)
#pragma unroll
                for (int jj = 0; jj < 4; ++jj)
                    acc[ii][jj] = fmaf(a[ii], bl[jj], acc[ii][jj]);
        }
        __syncthreads();
    }
#pragma unroll
    for (int ii = 0; ii < 4; ++ii) {
        int row = r0 + ty * 4 + ii;
        int b = row >> 10, n = row & 1023;
        float* orow = out + (((size_t)(b * NH + h)) * NTOK + n) * HDIM;
#pragma unroll
        for (int jj = 0; jj < 4; ++jj) {
            int d = tx * 4 + jj;
            orow[d] = acc[ii][jj] + bias[h * HDIM + d];
        }
    }
}

// ---------------- streaming sigmoid attention ----------------
// per (b,h): O = sigmoid(Q K^T / 8) V ; writes O into [B,N,C] concat layout
__global__ __launch_bounds__(256) void k_attn(
    const float* __restrict__ q, const float* __restrict__ k,
    const float* __restrict__ v, float* __restrict__ o) {
    __shared__ float Qs[64][65];
    __shared__ float Ks[32][65];
    __shared__ float Vs[32][64];
    __shared__ float Zs[64][33];
    int b = blockIdx.z, h = blockIdx.y;
    int i0 = blockIdx.x * 64;
    size_t base = ((size_t)(b * NH + h)) * NTOK * HDIM;
    const float* qp = q + base + (size_t)i0 * HDIM;
    const float* kp = k + base;
    const float* vp = v + base;
    int t = threadIdx.x, ty = t >> 4, tx = t & 15;
    for (int idx = t; idx < 1024; idx += 256) {
        int r = idx >> 4, d = (idx & 15) * 4;
        float4 qv4 = *(const float4*)&qp[idx * 4];
        Qs[r][d + 0] = qv4.x; Qs[r][d + 1] = qv4.y;
        Qs[r][d + 2] = qv4.z; Qs[r][d + 3] = qv4.w;
    }
    float acc[4][4] = {};
    for (int kt = 0; kt < 32; ++kt) {
        __syncthreads();  // prev iter done reading Ks/Vs/Zs (also fences Qs on kt=0)
        for (int idx = t; idx < 512; idx += 256) {
            int r = idx >> 4, d = (idx & 15) * 4;
            float4 kv4 = *(const float4*)&kp[kt * 2048 + idx * 4];
            Ks[r][d + 0] = kv4.x; Ks[r][d + 1] = kv4.y;
            Ks[r][d + 2] = kv4.z; Ks[r][d + 3] = kv4.w;
            float4 vv4 = *(const float4*)&vp[kt * 2048 + idx * 4];
            *(float4*)&Vs[r][d] = vv4;
        }
        __syncthreads();
        float s[4][2] = {};
#pragma unroll 8
        for (int d = 0; d < 64; ++d) {
            float k0v = Ks[tx * 2 + 0][d], k1v = Ks[tx * 2 + 1][d];
#pragma unroll
            for (int ii = 0; ii < 4; ++ii) {
                float qv = Qs[ty * 4 + ii][d];
                s[ii][0] = fmaf(qv, k0v, s[ii][0]);
                s[ii][1] = fmaf(qv, k1v, s[ii][1]);
            }
        }
#pragma unroll
        for (int ii = 0; ii < 4; ++ii) {
            Zs[ty * 4 + ii][tx * 2 + 0] = 1.0f / (1.0f + expf(-s[ii][0] * 0.125f));
            Zs[ty * 4 + ii][tx * 2 + 1] = 1.0f / (1.0f + expf(-s[ii][1] * 0.125f));
        }
        __syncthreads();
#pragma unroll 4
        for (int j = 0; j < 32; ++j) {
            float4 vv = *(const float4*)&Vs[j][tx * 4];
#pragma unroll
            for (int ii = 0; ii < 4; ++ii) {
                float z = Zs[ty * 4 + ii][j];
                acc[ii][0] = fmaf(z, vv.x, acc[ii][0]);
                acc[ii][1] = fmaf(z, vv.y, acc[ii][1]);
                acc[ii][2] = fmaf(z, vv.z, acc[ii][2]);
                acc[ii][3] = fmaf(z, vv.w, acc[ii][3]);
            }
        }
    }
#pragma unroll
    for (int ii = 0; ii < 4; ++ii) {
        size_t orow = ((size_t)b * NTOK + i0 + ty * 4 + ii) * CDIM + h * HDIM;
#pragma unroll
        for (int jj = 0; jj < 4; ++jj)
            o[orow + tx * 4 + jj] = acc[ii][jj];
    }
}

// ---------------- generic GEMM: D = A@B + bias (+ rscale*resid) (+gelu) ----------------
__global__ __launch_bounds__(256) void k_gemm(
    const float* __restrict__ A, const float* __restrict__ Bm,
    const float* __restrict__ bias, const float* __restrict__ resid,
    const float* __restrict__ rscale, float* __restrict__ D,
    int Ncols, int Kd, int act) {
    __shared__ float As[64][17];
    __shared__ float Bs[16][64];
    int t = threadIdx.x;
    int ty = t >> 4, tx = t & 15;
    int r0 = blockIdx.x * 64;
    int n0 = blockIdx.y * 64;
    float acc[4][4] = {};
    int la_row = t >> 2, la_k = (t & 3) * 4;
    int lb_k = t >> 4, lb_n = (t & 15) * 4;
    for (int k0 = 0; k0 < Kd; k0 += 16) {
        float4 av = *(const float4*)&A[(size_t)(r0 + la_row) * Kd + k0 + la_k];
        As[la_row][la_k + 0] = av.x; As[la_row][la_k + 1] = av.y;
        As[la_row][la_k + 2] = av.z; As[la_row][la_k + 3] = av.w;
        float4 bv4 = *(const float4*)&Bm[(size_t)(k0 + lb_k) * Ncols + n0 + lb_n];
        *(float4*)&Bs[lb_k][lb_n] = bv4;
        __syncthreads();
#pragma unroll
        for (int kk = 0; kk < 16; ++kk) {
            float a[4];
#pragma unroll
            for (int ii = 0; ii < 4; ++ii) a[ii] = As[ty * 4 + ii][kk];
            float4 bb = *(const float4*)&Bs[kk][tx * 4];
            float bl[4] = {bb.x, bb.y, bb.z, bb.w};
#pragma unroll
            for (int ii = 0; ii < 4; ++ii)
#pragma unroll
                for (int jj = 0; jj < 4; ++jj)
                    acc[ii][jj] = fmaf(a[ii], bl[jj], acc[ii][jj]);
        }
        __syncthreads();
    }
#pragma unroll
    for (int ii = 0; ii < 4; ++ii) {
        int row = r0 + ty * 4 + ii;
        float* drow = D + (size_t)row * Ncols;
        const float* rrow = resid ? resid + (size_t)row * Ncols : nullptr;
#pragma unroll
        for (int jj = 0; jj < 4; ++jj) {
            int col = n0 + tx * 4 + jj;
            float val = acc[ii][jj] + bias[col];
            if (rrow) val += rscale[col] * rrow[col];
            if (act) val = 0.5f * val * (1.0f + erff(val * 0.70710678118f));
            drow[col] = val;
        }
    }
}

// ---------------- depthwise conv (in [B,N,C] token layout) ----------------
__global__ __launch_bounds__(256) void k_dwconv(
    const float* __restrict__ in, const float* __restrict__ w,
    const float* __restrict__ bias, float* __restrict__ out, int K, int pad) {
    int b = blockIdx.y, n = blockIdx.x;
    int i = n >> 5, j = n & 31;
    int t = threadIdx.x;
    int c0 = t, c1 = t + 256, c2 = t + 512;
    float a0 = bias[c0], a1 = bias[c1], a2 = bias[c2];
    int KK = K * K;
    for (int di = 0; di < K; ++di) {
        int ii = i + di - pad;
        if (ii < 0 || ii >= 32) continue;
        for (int dj = 0; dj < K; ++dj) {
            int jj = j + dj - pad;
            if (jj < 0 || jj >= 32) continue;
            const float* xr = in + ((size_t)b * NTOK + ii * 32 + jj) * CDIM;
            int wo = di * K + dj;
            a0 = fmaf(xr[c0], w[c0 * KK + wo], a0);
            a1 = fmaf(xr[c1], w[c1 * KK + wo], a1);
            a2 = fmaf(xr[c2], w[c2 * KK + wo], a2);
        }
    }
    float* orow = out + ((size_t)b * NTOK + n) * CDIM;
    orow[c0] = a0; orow[c1] = a1; orow[c2] = a2;
}

// ---------------- layernorm over C=768 ----------------
__global__ __launch_bounds__(256) void k_ln(
    const float* __restrict__ in, const float* __restrict__ g,
    const float* __restrict__ b, float* __restrict__ out) {
    int row = blockIdx.x;
    const float* xr = in + (size_t)row * CDIM;
    int t = threadIdx.x;
    float x0 = xr[t], x1 = xr[t + 256], x2 = xr[t + 512];
    float s = x0 + x1 + x2;
    float sq = x0 * x0 + x1 * x1 + x2 * x2;
#pragma unroll
    for (int off = 32; off > 0; off >>= 1) {
        s += __shfl_down(s, off);
        sq += __shfl_down(sq, off);
    }
    __shared__ float ws[4], wq2[4];
    int wid = t >> 6, lane = t & 63;
    if (lane == 0) { ws[wid] = s; wq2[wid] = sq; }
    __syncthreads();
    if (t == 0) {
        float S = ws[0] + ws[1] + ws[2] + ws[3];
        float Q = wq2[0] + wq2[1] + wq2[2] + wq2[3];
        float m = S * (1.0f / CDIM);
        float var = Q * (1.0f / CDIM) - m * m;
        ws[0] = m;
        wq2[0] = rsqrtf(var + 1e-5f);
    }
    __syncthreads();
    float m = ws[0], inv = wq2[0];
    float* orow = out + (size_t)row * CDIM;
    orow[t] = (x0 - m) * inv * g[t] + b[t];
    orow[t + 256] = (x1 - m) * inv * g[t + 256] + b[t + 256];
    orow[t + 512] = (x2 - m) * inv * g[t + 512] + b[t + 512];
}

// ---------------- final combine + transpose back to [B,C,N] ----------------
__global__ void k_final(const float* __restrict__ y, const float* __restrict__ xln,
                        const float* __restrict__ scale, const float* __restrict__ alph,
                        float* __restrict__ out) {
    __shared__ float tile[32][33];
    int b = blockIdx.z, n0 = blockIdx.x * 32, c0 = blockIdx.y * 32;
    int tx = threadIdx.x, ty = threadIdx.y;
#pragma unroll
    for (int r = 0; r < 4; ++r) {
        int n = n0 + ty + r * 8, c = c0 + tx;
        size_t idx = ((size_t)b * NTOK + n) * CDIM + c;
        tile[tx][ty + r * 8] = scale[c] * y[idx] + alph[c] * xln[idx];
    }
    __syncthreads();
#pragma unroll
    for (int r = 0; r < 4; ++r) {
        int c = c0 + ty + r * 8;
        out[((size_t)b * CDIM + c) * NTOK + n0 + tx] = tile[ty + r * 8][tx];
    }
}

extern "C" void kernel_launch(void* const* d_in, const int* in_sizes, int n_in,
                              void* d_out, int out_size, void* d_ws, size_t ws_size,
                              hipStream_t stream) {
    const float* dec = (const float*)d_in[0];
    const float* wq1 = (const float*)d_in[1]; const float* bq1 = (const float*)d_in[2];
    const float* wk1 = (const float*)d_in[3]; const float* bk1 = (const float*)d_in[4];
    const float* wv1 = (const float*)d_in[5]; const float* bv1 = (const float*)d_in[6];
    const float* wo1 = (const float*)d_in[7]; const float* bo1 = (const float*)d_in[8];
    const float* wq2 = (const float*)d_in[9]; const float* bq2 = (const float*)d_in[10];
    const float* wk2 = (const float*)d_in[11]; const float* bk2 = (const float*)d_in[12];
    const float* wv2 = (const float*)d_in[13]; const float* bv2 = (const float*)d_in[14];
    const float* wo2 = (const float*)d_in[15]; const float* bo2 = (const float*)d_in[16];
    const float* alphas1 = (const float*)d_in[17];
    const float* alphas2 = (const float*)d_in[18];
    const float* peg_w = (const float*)d_in[19]; const float* peg_b = (const float*)d_in[20];
    const float* ln1_g = (const float*)d_in[21]; const float* ln1_b = (const float*)d_in[22];
    const float* ln2_g = (const float*)d_in[23]; const float* ln2_b = (const float*)d_in[24];
    const float* cn_dw_w = (const float*)d_in[25]; const float* cn_dw_b = (const float*)d_in[26];
    const float* cn_ln_g = (const float*)d_in[27]; const float* cn_ln_b = (const float*)d_in[28];
    const float* cn_w1 = (const float*)d_in[29]; const float* cn_b1 = (const float*)d_in[30];
    const float* cn_w2 = (const float*)d_in[31]; const float* cn_b2 = (const float*)d_in[32];
    const float* cn_scale = (const float*)d_in[33]; const float* cn_alphas = (const float*)d_in[34];
    float* out = (float*)d_out;
    float* ws = (float*)d_ws;

    const size_t S = (size_t)BATCH * NTOK * CDIM;  // 6.29M floats
    float* A0 = ws;
    float* A1 = ws + S;
    float* Qb = ws + 2 * S;
    float* Kb = ws + 3 * S;
    float* Vb = ws + 4 * S;
    float* Ob = ws + 5 * S;
    float* Hc = ws + 6 * S;  // 2048x3072 chunk

    dim3 tb(32, 8);
    // x = transpose(decoder)
    k_transpose_in<<<dim3(32, 24, 8), tb, 0, stream>>>(dec, A0);
    // block 1
    k_qkv<<<dim3(128, 36), 256, 0, stream>>>(A0, wq1, bq1, wk1, bk1, wv1, bv1, Qb, Kb, Vb);
    k_attn<<<dim3(16, 12, 8), 256, 0, stream>>>(Qb, Kb, Vb, Ob);
    k_gemm<<<dim3(128, 12), 256, 0, stream>>>(Ob, wo1, bo1, A0, alphas1, A1, 768, 768, 0);
    // PEG dwconv3x3 (replaces x)
    k_dwconv<<<dim3(1024, 8), 256, 0, stream>>>(A1, peg_w, peg_b, A0, 3, 1);
    k_ln<<<8192, 256, 0, stream>>>(A0, ln1_g, ln1_b, A1);
    // block 2
    k_qkv<<<dim3(128, 36), 256, 0, stream>>>(A1, wq2, bq2, wk2, bk2, wv2, bv2, Qb, Kb, Vb);
    k_attn<<<dim3(16, 12, 8), 256, 0, stream>>>(Qb, Kb, Vb, Ob);
    k_gemm<<<dim3(128, 12), 256, 0, stream>>>(Ob, wo2, bo2, A1, alphas2, A0, 768, 768, 0);
    k_ln<<<8192, 256, 0, stream>>>(A0, ln2_g, ln2_b, A1);  // A1 = xln2 (preserved)
    // CNBlock head
    k_dwconv<<<dim3(1024, 8), 256, 0, stream>>>(A1, cn_dw_w, cn_dw_b, A0, 7, 3);
    k_ln<<<8192, 256, 0, stream>>>(A0, cn_ln_g, cn_ln_b, Ob);  // Ob = LN'd conv out
    // MLP chunked (2048 rows per chunk)
    for (int ch = 0; ch < 4; ++ch) {
        const float* src = Ob + (size_t)ch * 2048 * CDIM;
        float* dst = Qb + (size_t)ch * 2048 * CDIM;
        k_gemm<<<dim3(32, 48), 256, 0, stream>>>(src, cn_w1, cn_b1, nullptr, nullptr, Hc, 3072, 768, 1);
        k_gemm<<<dim3(32, 12), 256, 0, stream>>>(Hc, cn_w2, cn_b2, nullptr, nullptr, dst, 768, 3072, 0);
    }
    // out = cn_scale*y + cn_alphas*xln2, transposed to [B,C,H,W]
    k_final<<<dim3(32, 24, 8), tb, 0, stream>>>(Qb, A1, cn_scale, cn_alphas, out);
}

// Round 2
// 3673.569 us; speedup vs baseline: 1.3127x; 1.3127x over previous
//
#include <hip/hip_runtime.h>
#include <math.h>

#define BATCH 8
#define CDIM 768
#define NTOK 1024
#define NH 12
#define HDIM 64
#define MROWS (BATCH * NTOK)   // 8192

// ---------------- transpose [B,C,N] -> [B,N,C] ----------------
__global__ void k_transpose_in(const float* __restrict__ dec, float* __restrict__ x) {
    __shared__ float tile[32][33];
    int b = blockIdx.z;
    int n0 = blockIdx.x * 32;
    int c0 = blockIdx.y * 32;
    int tx = threadIdx.x, ty = threadIdx.y;
#pragma unroll
    for (int r = 0; r < 4; ++r) {
        int c = c0 + ty + r * 8;
        tile[ty + r * 8][tx] = dec[((size_t)b * CDIM + c) * NTOK + n0 + tx];
    }
    __syncthreads();
#pragma unroll
    for (int r = 0; r < 4; ++r) {
        int n = n0 + ty + r * 8;
        x[((size_t)b * NTOK + n) * CDIM + c0 + tx] = tile[tx][ty + r * 8];
    }
}

// ---------------- QKV projection (gathered GEMM) ----------------
// x:[8192,768] @ per-head W -> q/k/v in [B,H,N,64]
__global__ __launch_bounds__(256) void k_qkv(
    const float* __restrict__ x,
    const float* __restrict__ wq, const float* __restrict__ bq,
    const float* __restrict__ wk, const float* __restrict__ bk,
    const float* __restrict__ wv, const float* __restrict__ bv,
    float* __restrict__ q, float* __restrict__ k_, float* __restrict__ v) {
    __shared__ float As[64][17];
    __shared__ float Bs[16][64];
    int t = threadIdx.x;
    int ty = t >> 4, tx = t & 15;
    int r0 = blockIdx.x * 64;
    int by = blockIdx.y;  // 0..35
    int sect = by / NH, h = by % NH;
    const float* W; const float* bias; float* out;
    if (sect == 0)      { W = wq; bias = bq; out = q; }
    else if (sect == 1) { W = wk; bias = bk; out = k_; }
    else                { W = wv; bias = bv; out = v; }
    const float* Wh = W + (size_t)h * CDIM * HDIM;  // [768][64]
    float acc[4][4] = {};
    int la_row = t >> 2, la_k = (t & 3) * 4;
    int lb_k = t >> 4, lb_n = (t & 15) * 4;
    for (int k0 = 0; k0 < CDIM; k0 += 16) {
        float4 av = *(const float4*)&x[(size_t)(r0 + la_row) * CDIM + k0 + la_k];
        As[la_row][la_k + 0] = av.x; As[la_row][la_k + 1] = av.y;
        As[la_row][la_k + 2] = av.z; As[la_row][la_k + 3] = av.w;
        float4 bv4 = *(const float4*)&Wh[(size_t)(k0 + lb_k) * HDIM + lb_n];
        *(float4*)&Bs[lb_k][lb_n] = bv4;
        __syncthreads();
#pragma unroll
        for (int kk = 0; kk < 16; ++kk) {
            float a[4];
#pragma unroll
            for (int ii = 0; ii < 4; ++ii) a[ii] = As[ty * 4 + ii][kk];
            float4 bb = *(const float4*)&Bs[kk][tx * 4];
            float bl[4] = {bb.x, bb.y, bb.z, bb.w};
#pragma unroll
            for (int ii = 0; ii < 4; ++ii)
#pragma unroll
                for (int jj = 0; jj < 4; ++jj)
                    acc[ii][jj] = fmaf(a[ii], bl[jj], acc[ii][jj]);
        }
        __syncthreads();
    }
#pragma unroll
    for (int ii = 0; ii < 4; ++ii) {
        int row = r0 + ty * 4 + ii;
        int b = row >> 10, n = row & 1023;
        float* orow = out + (((size_t)(b * NH + h)) * NTOK + n) * HDIM;
#pragma unroll
        for (int jj = 0; jj < 4; ++jj) {
            int d = tx * 4 + jj;
            orow[d] = acc[ii][jj] + bias[h * HDIM + d];
        }
    }
}

// ---------------- streaming sigmoid attention ----------------
// per (b,h): O = sigmoid(Q K^T / 8) V ; writes O into [B,N,C] concat layout
__global__ __launch_bounds__(256) void k_attn(
    const float* __restrict__ q, const float* __restrict__ k,
    const float* __restrict__ v, float* __restrict__ o) {
    __shared__ float Qs[64][65];
    __shared__ float Ks[32][65];
    __shared__ float Vs[32][64];
    __shared__ float Zs[64][33];
    int b = blockIdx.z, h = blockIdx.y;
    int i0 = blockIdx.x * 64;
    size_t base = ((size_t)(b * NH + h)) * NTOK * HDIM;
    const float* qp = q + base + (size_t)i0 * HDIM;
    const float* kp = k + base;
    const float* vp = v + base;
    int t = threadIdx.x, ty = t >> 4, tx = t & 15;
    for (int idx = t; idx < 1024; idx += 256) {
        int r = idx >> 4, d = (idx & 15) * 4;
        float4 qv4 = *(const float4*)&qp[idx * 4];
        Qs[r][d + 0] = qv4.x; Qs[r][d + 1] = qv4.y;
        Qs[r][d + 2] = qv4.z; Qs[r][d + 3] = qv4.w;
    }
    float acc[4][4] = {};
    for (int kt = 0; kt < 32; ++kt) {
        __syncthreads();  // prev iter done reading Ks/Vs/Zs (also fences Qs on kt=0)
        for (int idx = t; idx < 512; idx += 256) {
            int r = idx >> 4, d = (idx & 15) * 4;
            float4 kv4 = *(const float4*)&kp[kt * 2048 + idx * 4];
            Ks[r][d + 0] = kv4.x; Ks[r][d + 1] = kv4.y;
            Ks[r][d + 2] = kv4.z; Ks[r][d + 3] = kv4.w;
            float4 vv4 = *(const float4*)&vp[kt * 2048 + idx * 4];
            *(float4*)&Vs[r][d] = vv4;
        }
        __syncthreads();
        float s[4][2] = {};
#pragma unroll 8
        for (int d = 0; d < 64; ++d) {
            float k0v = Ks[tx * 2 + 0][d], k1v = Ks[tx * 2 + 1][d];
#pragma unroll
            for (int ii = 0; ii < 4; ++ii) {
                float qv = Qs[ty * 4 + ii][d];
                s[ii][0] = fmaf(qv, k0v, s[ii][0]);
                s[ii][1] = fmaf(qv, k1v, s[ii][1]);
            }
        }
#pragma unroll
        for (int ii = 0; ii < 4; ++ii) {
            Zs[ty * 4 + ii][tx * 2 + 0] = 1.0f / (1.0f + expf(-s[ii][0] * 0.125f));
            Zs[ty * 4 + ii][tx * 2 + 1] = 1.0f / (1.0f + expf(-s[ii][1] * 0.125f));
        }
        __syncthreads();
#pragma unroll 4
        for (int j = 0; j < 32; ++j) {
            float4 vv = *(const float4*)&Vs[j][tx * 4];
#pragma unroll
            for (int ii = 0; ii < 4; ++ii) {
                float z = Zs[ty * 4 + ii][j];
                acc[ii][0] = fmaf(z, vv.x, acc[ii][0]);
                acc[ii][1] = fmaf(z, vv.y, acc[ii][1]);
                acc[ii][2] = fmaf(z, vv.z, acc[ii][2]);
                acc[ii][3] = fmaf(z, vv.w, acc[ii][3]);
            }
        }
    }
#pragma unroll
    for (int ii = 0; ii < 4; ++ii) {
        size_t orow = ((size_t)b * NTOK + i0 + ty * 4 + ii) * CDIM + h * HDIM;
#pragma unroll
        for (int jj = 0; jj < 4; ++jj)
            o[orow + tx * 4 + jj] = acc[ii][jj];
    }
}

// ---------------- generic GEMM: D = A@B + bias (+ rscale*resid) (+gelu) ----------------
__global__ __launch_bounds__(256) void k_gemm(
    const float* __restrict__ A, const float* __restrict__ Bm,
    const float* __restrict__ bias, const float* __restrict__ resid,
    const float* __restrict__ rscale, float* __restrict__ D,
    int Ncols, int Kd, int act) {
    __shared__ float As[64][17];
    __shared__ float Bs[16][64];
    int t = threadIdx.x;
    int ty = t >> 4, tx = t & 15;
    int r0 = blockIdx.x * 64;
    int n0 = blockIdx.y * 64;
    float acc[4][4] = {};
    int la_row = t >> 2, la_k = (t & 3) * 4;
    int lb_k = t >> 4, lb_n = (t & 15) * 4;
    for (int k0 = 0; k0 < Kd; k0 += 16) {
        float4 av = *(const float4*)&A[(size_t)(r0 + la_row) * Kd + k0 + la_k];
        As[la_row][la_k + 0] = av.x; As[la_row][la_k + 1] = av.y;
        As[la_row][la_k + 2] = av.z; As[la_row][la_k + 3] = av.w;
        float4 bv4 = *(const float4*)&Bm[(size_t)(k0 + lb_k) * Ncols + n0 + lb_n];
        *(float4*)&Bs[lb_k][lb_n] = bv4;
        __syncthreads();
#pragma unroll
        for (int kk = 0; kk < 16; ++kk) {
            float a[4];
#pragma unroll
            for (int ii = 0; ii < 4; ++ii) a[ii] = As[ty * 4 + ii][kk];
            float4 bb = *(const float4*)&Bs[kk][tx * 4];
            float bl[4] = {bb.x, bb.y, bb.z, bb.w};
#pragma unroll
            for (int ii = 0; ii < 4; ++ii)
#pragma unroll
                for (int jj = 0; jj < 4; ++jj)
                    acc[ii][jj] = fmaf(a[ii], bl[jj], acc[ii][jj]);
        }
        __syncthreads();
    }
#pragma unroll
    for (int ii = 0; ii < 4; ++ii) {
        int row = r0 + ty * 4 + ii;
        float* drow = D + (size_t)row * Ncols;
        const float* rrow = resid ? resid + (size_t)row * Ncols : nullptr;
#pragma unroll
        for (int jj = 0; jj < 4; ++jj) {
            int col = n0 + tx * 4 + jj;
            float val = acc[ii][jj] + bias[col];
            if (rrow) val += rscale[col] * rrow[col];
            if (act) val = 0.5f * val * (1.0f + erff(val * 0.70710678118f));
            drow[col] = val;
        }
    }
}

// ---------------- depthwise conv, register sliding window ----------------
// layout [B,N=32x32,C]; thread = (channel c, pixel column j); sweeps rows i=0..31
// block: 256 thr = 64 channels x 4 columns. grid = (8 col-groups, 12 ch-groups, B)
template<int K>
__global__ __launch_bounds__(256) void k_dwconv_t(
    const float* __restrict__ in, const float* __restrict__ w,
    const float* __restrict__ bias, float* __restrict__ out) {
    constexpr int PAD = K / 2;
    constexpr int KK = K * K;
    int t = threadIdx.x;
    int c = blockIdx.y * 64 + (t & 63);
    int j = blockIdx.x * 4 + (t >> 6);
    int b = blockIdx.z;
    float wr[KK];
#pragma unroll
    for (int q = 0; q < KK; ++q) wr[q] = w[(size_t)c * KK + q];
    float bsv = bias[c];
    const float* base = in + (size_t)b * NTOK * CDIM + c;
    float win[K][K];
    // pre-fill: win[s] (s=1..K-1) holds input row (s-1-PAD), cols j-PAD..j+PAD
#pragma unroll
    for (int s = 1; s < K; ++s) {
        int ii = s - 1 - PAD;
#pragma unroll
        for (int q = 0; q < K; ++q) {
            int jj = j - PAD + q;
            win[s][q] = (ii >= 0 && jj >= 0 && jj < 32)
                        ? base[(size_t)(ii * 32 + jj) * CDIM] : 0.0f;
        }
    }
#pragma unroll
    for (int i = 0; i < 32; ++i) {
        // shift window up
#pragma unroll
        for (int r = 0; r < K - 1; ++r)
#pragma unroll
            for (int q = 0; q < K; ++q) win[r][q] = win[r + 1][q];
        // load new bottom row i+PAD
        int ii = i + PAD;
#pragma unroll
        for (int q = 0; q < K; ++q) {
            int jj = j - PAD + q;
            win[K - 1][q] = (ii < 32 && jj >= 0 && jj < 32)
                            ? base[(size_t)(ii * 32 + jj) * CDIM] : 0.0f;
        }
        float acc = bsv;
#pragma unroll
        for (int r = 0; r < K; ++r)
#pragma unroll
            for (int q = 0; q < K; ++q)
                acc = fmaf(win[r][q], wr[r * K + q], acc);
        out[((size_t)b * NTOK + i * 32 + j) * CDIM + c] = acc;
    }
}

// ---------------- layernorm over C=768 ----------------
__global__ __launch_bounds__(256) void k_ln(
    const float* __restrict__ in, const float* __restrict__ g,
    const float* __restrict__ b, float* __restrict__ out) {
    int row = blockIdx.x;
    const float* xr = in + (size_t)row * CDIM;
    int t = threadIdx.x;
    float x0 = xr[t], x1 = xr[t + 256], x2 = xr[t + 512];
    float s = x0 + x1 + x2;
    float sq = x0 * x0 + x1 * x1 + x2 * x2;
#pragma unroll
    for (int off = 32; off > 0; off >>= 1) {
        s += __shfl_down(s, off);
        sq += __shfl_down(sq, off);
    }
    __shared__ float ws[4], wq2[4];
    int wid = t >> 6, lane = t & 63;
    if (lane == 0) { ws[wid] = s; wq2[wid] = sq; }
    __syncthreads();
    if (t == 0) {
        float S = ws[0] + ws[1] + ws[2] + ws[3];
        float Q = wq2[0] + wq2[1] + wq2[2] + wq2[3];
        float m = S * (1.0f / CDIM);
        float var = Q * (1.0f / CDIM) - m * m;
        ws[0] = m;
        wq2[0] = rsqrtf(var + 1e-5f);
    }
    __syncthreads();
    float m = ws[0], inv = wq2[0];
    float* orow = out + (size_t)row * CDIM;
    orow[t] = (x0 - m) * inv * g[t] + b[t];
    orow[t + 256] = (x1 - m) * inv * g[t + 256] + b[t + 256];
    orow[t + 512] = (x2 - m) * inv * g[t + 512] + b[t + 512];
}

// ---------------- final combine + transpose back to [B,C,N] ----------------
__global__ void k_final(const float* __restrict__ y, const float* __restrict__ xln,
                        const float* __restrict__ scale, const float* __restrict__ alph,
                        float* __restrict__ out) {
    __shared__ float tile[32][33];
    int b = blockIdx.z, n0 = blockIdx.x * 32, c0 = blockIdx.y * 32;
    int tx = threadIdx.x, ty = threadIdx.y;
#pragma unroll
    for (int r = 0; r < 4; ++r) {
        int n = n0 + ty + r * 8, c = c0 + tx;
        size_t idx = ((size_t)b * NTOK + n) * CDIM + c;
        tile[tx][ty + r * 8] = scale[c] * y[idx] + alph[c] * xln[idx];
    }
    __syncthreads();
#pragma unroll
    for (int r = 0; r < 4; ++r) {
        int c = c0 + ty + r * 8;
        out[((size_t)b * CDIM + c) * NTOK + n0 + tx] = tile[ty + r * 8][tx];
    }
}

extern "C" void kernel_launch(void* const* d_in, const int* in_sizes, int n_in,
                              void* d_out, int out_size, void* d_ws, size_t ws_size,
                              hipStream_t stream) {
    const float* dec = (const float*)d_in[0];
    const float* wq1 = (const float*)d_in[1]; const float* bq1 = (const float*)d_in[2];
    const float* wk1 = (const float*)d_in[3]; const float* bk1 = (const float*)d_in[4];
    const float* wv1 = (const float*)d_in[5]; const float* bv1 = (const float*)d_in[6];
    const float* wo1 = (const float*)d_in[7]; const float* bo1 = (const float*)d_in[8];
    const float* wq2 = (const float*)d_in[9]; const float* bq2 = (const float*)d_in[10];
    const float* wk2 = (const float*)d_in[11]; const float* bk2 = (const float*)d_in[12];
    const float* wv2 = (const float*)d_in[13]; const float* bv2 = (const float*)d_in[14];
    const float* wo2 = (const float*)d_in[15]; const float* bo2 = (const float*)d_in[16];
    const float* alphas1 = (const float*)d_in[17];
    const float* alphas2 = (const float*)d_in[18];
    const float* peg_w = (const float*)d_in[19]; const float* peg_b = (const float*)d_in[20];
    const float* ln1_g = (const float*)d_in[21]; const float* ln1_b = (const float*)d_in[22];
    const float* ln2_g = (const float*)d_in[23]; const float* ln2_b = (const float*)d_in[24];
    const float* cn_dw_w = (const float*)d_in[25]; const float* cn_dw_b = (const float*)d_in[26];
    const float* cn_ln_g = (const float*)d_in[27]; const float* cn_ln_b = (const float*)d_in[28];
    const float* cn_w1 = (const float*)d_in[29]; const float* cn_b1 = (const float*)d_in[30];
    const float* cn_w2 = (const float*)d_in[31]; const float* cn_b2 = (const float*)d_in[32];
    const float* cn_scale = (const float*)d_in[33]; const float* cn_alphas = (const float*)d_in[34];
    float* out = (float*)d_out;
    float* ws = (float*)d_ws;

    const size_t S = (size_t)BATCH * NTOK * CDIM;  // 6.29M floats
    float* A0 = ws;
    float* A1 = ws + S;
    float* Qb = ws + 2 * S;
    float* Kb = ws + 3 * S;
    float* Vb = ws + 4 * S;
    float* Ob = ws + 5 * S;
    float* Hc = ws + 6 * S;  // 2048x3072 chunk

    dim3 tb(32, 8);
    dim3 dwgrid(8, 12, 8);
    // x = transpose(decoder)
    k_transpose_in<<<dim3(32, 24, 8), tb, 0, stream>>>(dec, A0);
    // block 1
    k_qkv<<<dim3(128, 36), 256, 0, stream>>>(A0, wq1, bq1, wk1, bk1, wv1, bv1, Qb, Kb, Vb);
    k_attn<<<dim3(16, 12, 8), 256, 0, stream>>>(Qb, Kb, Vb, Ob);
    k_gemm<<<dim3(128, 12), 256, 0, stream>>>(Ob, wo1, bo1, A0, alphas1, A1, 768, 768, 0);
    // PEG dwconv3x3 (replaces x)
    k_dwconv_t<3><<<dwgrid, 256, 0, stream>>>(A1, peg_w, peg_b, A0);
    k_ln<<<8192, 256, 0, stream>>>(A0, ln1_g, ln1_b, A1);
    // block 2
    k_qkv<<<dim3(128, 36), 256, 0, stream>>>(A1, wq2, bq2, wk2, bk2, wv2, bv2, Qb, Kb, Vb);
    k_attn<<<dim3(16, 12, 8), 256, 0, stream>>>(Qb, Kb, Vb, Ob);
    k_gemm<<<dim3(128, 12), 256, 0, stream>>>(Ob, wo2, bo2, A1, alphas2, A0, 768, 768, 0);
    k_ln<<<8192, 256, 0, stream>>>(A0, ln2_g, ln2_b, A1);  // A1 = xln2 (preserved)
    // CNBlock head
    k_dwconv_t<7><<<dwgrid, 256, 0, stream>>>(A1, cn_dw_w, cn_dw_b, A0);
    k_ln<<<8192, 256, 0, stream>>>(A0, cn_ln_g, cn_ln_b, Ob);  // Ob = LN'd conv out
    // MLP chunked (2048 rows per chunk)
    for (int ch = 0; ch < 4; ++ch) {
        const float* src = Ob + (size_t)ch * 2048 * CDIM;
        float* dst = Qb + (size_t)ch * 2048 * CDIM;
        k_gemm<<<dim3(32, 48), 256, 0, stream>>>(src, cn_w1, cn_b1, nullptr, nullptr, Hc, 3072, 768, 1);
        k_gemm<<<dim3(32, 12), 256, 0, stream>>>(Hc, cn_w2, cn_b2, nullptr, nullptr, dst, 768, 3072, 0);
    }
    // out = cn_scale*y + cn_alphas*xln2, transposed to [B,C,H,W]
    k_final<<<dim3(32, 24, 8), tb, 0, stream>>>(Qb, A1, cn_scale, cn_alphas, out);
}

// Round 3
// 772.815 us; speedup vs baseline: 6.2401x; 4.7535x over previous
//
#include <hip/hip_runtime.h>
#include <math.h>

#define BATCH 8
#define CDIM 768
#define NTOK 1024
#define NH 12
#define HDIM 64

typedef __attribute__((ext_vector_type(8))) short bf16x8;
typedef __attribute__((ext_vector_type(4))) float f32x4;

__device__ inline short f2bf(float f) {
    union { float f; unsigned u; } v; v.f = f;
    unsigned r = (v.u + 0x7FFF + ((v.u >> 16) & 1)) >> 16;
    return (short)r;
}

// ---------------- transpose [B,C,N] -> [B,N,C], fp32 + bf16 mirror ----------------
__global__ void k_transpose_in(const float* __restrict__ dec, float* __restrict__ x,
                               short* __restrict__ xb) {
    __shared__ float tile[32][33];
    int b = blockIdx.z;
    int n0 = blockIdx.x * 32;
    int c0 = blockIdx.y * 32;
    int tx = threadIdx.x, ty = threadIdx.y;
#pragma unroll
    for (int r = 0; r < 4; ++r) {
        int c = c0 + ty + r * 8;
        tile[ty + r * 8][tx] = dec[((size_t)b * CDIM + c) * NTOK + n0 + tx];
    }
    __syncthreads();
#pragma unroll
    for (int r = 0; r < 4; ++r) {
        int n = n0 + ty + r * 8;
        float val = tile[tx][ty + r * 8];
        size_t idx = ((size_t)b * NTOK + n) * CDIM + c0 + tx;
        x[idx] = val;
        xb[idx] = f2bf(val);
    }
}

// ---------------- weight transpose fp32 [R,C] -> bf16 [C,R] ----------------
__global__ void k_wtrans(const float* __restrict__ src, short* __restrict__ dst,
                         int R, int C) {
    __shared__ float tile[32][33];
    int c0 = blockIdx.x * 32, r0 = blockIdx.y * 32;
    int tx = threadIdx.x, ty = threadIdx.y;
#pragma unroll
    for (int p = 0; p < 4; ++p)
        tile[ty + p * 8][tx] = src[(size_t)(r0 + ty + p * 8) * C + c0 + tx];
    __syncthreads();
#pragma unroll
    for (int p = 0; p < 4; ++p)
        dst[(size_t)(c0 + ty + p * 8) * R + r0 + tx] = f2bf(tile[tx][ty + p * 8]);
}

// ---------------- pack per-head qkv weights -> [2304,768] bf16 (n = sect*768+h*64+d) ----
__global__ __launch_bounds__(256) void k_packqkv(
    const float* __restrict__ wq1, const float* __restrict__ wk1, const float* __restrict__ wv1,
    const float* __restrict__ wq2, const float* __restrict__ wk2, const float* __restrict__ wv2,
    short* __restrict__ dst1, short* __restrict__ dst2) {
    __shared__ float tile[64][65];
    int z = blockIdx.y;                 // 0..71
    int set = z / 36, rem = z % 36, sect = rem / 12, h = rem % 12;
    const float* srcs[6] = {wq1, wk1, wv1, wq2, wk2, wv2};
    const float* src = srcs[set * 3 + sect] + (size_t)h * 768 * 64;
    short* dst = (set ? dst2 : dst1) + ((size_t)sect * 768 + h * 64) * 768;
    int k0 = blockIdx.x * 64;
    int t = threadIdx.x;
#pragma unroll
    for (int p = 0; p < 16; ++p) {
        int gid = t + p * 256;
        int r = gid >> 6, c = gid & 63;
        tile[r][c] = src[(size_t)(k0 + r) * 64 + c];
    }
    __syncthreads();
#pragma unroll
    for (int p = 0; p < 16; ++p) {
        int gid = t + p * 256;
        int d = gid >> 6, kk = gid & 63;
        dst[(size_t)d * 768 + k0 + kk] = f2bf(tile[kk][d]);
    }
}

__global__ void k_packbias(const float* __restrict__ bq1, const float* __restrict__ bk1,
                           const float* __restrict__ bv1, const float* __restrict__ bq2,
                           const float* __restrict__ bk2, const float* __restrict__ bv2,
                           float* __restrict__ d1, float* __restrict__ d2) {
    int tid = blockIdx.x * 256 + threadIdx.x;
    if (tid >= 4608) return;
    int set = tid / 2304, n = tid % 2304;
    int sect = n / 768, rem = n % 768;
    const float* srcs[6] = {bq1, bk1, bv1, bq2, bk2, bv2};
    float v = srcs[set * 3 + sect][rem];
    (set ? d2 : d1)[n] = v;
}

// ---------------- generic bf16 MFMA GEMM, 128x128 tile, BK=32 ----------------
// A [M,K] bf16 row-major; Bt [N,K] bf16 row-major (i.e. B transposed)
#define GM_PLAIN 0
#define GM_PROJ  1
#define GM_GELU  2
#define GM_QKV   3
#define QKVSEC ((size_t)BATCH * NH * NTOK * HDIM)  // 6291456

template<int MODE>
__global__ __launch_bounds__(256) void k_gemm_mfma(
    const short* __restrict__ A, const short* __restrict__ Bt,
    const float* __restrict__ bias, const float* __restrict__ resid,
    const float* __restrict__ rscale, float* __restrict__ outF,
    short* __restrict__ outB, int M, int N, int K) {
    __shared__ short As[128][40];
    __shared__ short Bs[128][40];
    int t = threadIdx.x;
    int w = t >> 6, lane = t & 63, l15 = lane & 15, quad = lane >> 4;
    int r0 = blockIdx.x * 128, n0 = blockIdx.y * 128;
    int wr = (w >> 1) * 64, wc = (w & 1) * 64;
    f32x4 acc[4][4];
#pragma unroll
    for (int i = 0; i < 4; ++i)
#pragma unroll
        for (int j = 0; j < 4; ++j) acc[i][j] = (f32x4){0.f, 0.f, 0.f, 0.f};
    int sr = t >> 2, sc = (t & 3) * 8;
    for (int k0 = 0; k0 < K; k0 += 32) {
        __syncthreads();
#pragma unroll
        for (int p = 0; p < 2; ++p) {
            int r = sr + p * 64;
            *(bf16x8*)&As[r][sc] = *(const bf16x8*)&A[(size_t)(r0 + r) * K + k0 + sc];
            *(bf16x8*)&Bs[r][sc] = *(const bf16x8*)&Bt[(size_t)(n0 + r) * K + k0 + sc];
        }
        __syncthreads();
        bf16x8 af[4], bf[4];
#pragma unroll
        for (int i = 0; i < 4; ++i) af[i] = *(const bf16x8*)&As[wr + i * 16 + l15][quad * 8];
#pragma unroll
        for (int j = 0; j < 4; ++j) bf[j] = *(const bf16x8*)&Bs[wc + j * 16 + l15][quad * 8];
#pragma unroll
        for (int i = 0; i < 4; ++i)
#pragma unroll
            for (int j = 0; j < 4; ++j)
                acc[i][j] = __builtin_amdgcn_mfma_f32_16x16x32_bf16(af[i], bf[j], acc[i][j], 0, 0, 0);
    }
#pragma unroll
    for (int i = 0; i < 4; ++i)
#pragma unroll
        for (int j = 0; j < 4; ++j)
#pragma unroll
            for (int rr = 0; rr < 4; ++rr) {
                int row = r0 + wr + i * 16 + quad * 4 + rr;
                int col = n0 + wc + j * 16 + l15;
                float val = acc[i][j][rr] + bias[col];
                if (MODE == GM_PROJ) {
                    val += rscale[col] * resid[(size_t)row * N + col];
                    outF[(size_t)row * N + col] = val;
                } else if (MODE == GM_GELU) {
                    val = 0.5f * val * (1.0f + erff(val * 0.70710678118f));
                    outB[(size_t)row * N + col] = f2bf(val);
                } else if (MODE == GM_PLAIN) {
                    outF[(size_t)row * N + col] = val;
                } else {  // GM_QKV: scatter into q/k/v [B,H,N,64]
                    int sect = col / 768, rem = col - sect * 768;
                    int hh = rem >> 6, d = rem & 63;
                    int bb = row >> 10, tok = row & 1023;
                    outB[(size_t)sect * QKVSEC +
                         (((size_t)bb * NH + hh) * NTOK + tok) * HDIM + d] = f2bf(val);
                }
            }
}

// ---------------- MFMA sigmoid attention ----------------
// per (b,h): O = sigmoid(QK^T/8) V ; q/k/v [B,H,N,64] bf16; O -> [B,N,C] bf16
__global__ __launch_bounds__(256) void k_attn_mfma(
    const short* __restrict__ q, const short* __restrict__ k,
    const short* __restrict__ v, short* __restrict__ o) {
    __shared__ short Ks[64][72];
    __shared__ short Vt[64][72];
    __shared__ short Ps[128][72];
    int b = blockIdx.z, h = blockIdx.y;
    int q0 = blockIdx.x * 128;
    int t = threadIdx.x;
    int w = t >> 6, lane = t & 63, l15 = lane & 15, quad = lane >> 4;
    size_t base = ((size_t)(b * NH + h)) * NTOK * HDIM;
    const short* qp = q + base;
    const short* kp = k + base;
    const short* vp = v + base;
    bf16x8 qf[2][2];
#pragma unroll
    for (int mt = 0; mt < 2; ++mt)
#pragma unroll
        for (int kc = 0; kc < 2; ++kc)
            qf[mt][kc] = *(const bf16x8*)&qp[(size_t)(q0 + w * 32 + mt * 16 + l15) * HDIM + kc * 32 + quad * 8];
    f32x4 oacc[2][4];
#pragma unroll
    for (int mt = 0; mt < 2; ++mt)
#pragma unroll
        for (int dt = 0; dt < 4; ++dt) oacc[mt][dt] = (f32x4){0.f, 0.f, 0.f, 0.f};
    for (int kt = 0; kt < 16; ++kt) {
        __syncthreads();
#pragma unroll
        for (int p = 0; p < 2; ++p) {
            int gid = t + p * 256;
            int r = gid >> 3, c8 = (gid & 7) * 8;
            *(bf16x8*)&Ks[r][c8] = *(const bf16x8*)&kp[(size_t)(kt * 64 + r) * HDIM + c8];
        }
#pragma unroll
        for (int p = 0; p < 2; ++p) {
            int tok = t & 63, d0 = (t >> 6) * 8 + p * 32;
            bf16x8 vv = *(const bf16x8*)&vp[(size_t)(kt * 64 + tok) * HDIM + d0];
#pragma unroll
            for (int j = 0; j < 8; ++j) Vt[d0 + j][tok] = vv[j];
        }
        __syncthreads();
        // S = Q K^T for this wave's 32 q-rows x 64 keys
        f32x4 sacc[2][4];
#pragma unroll
        for (int mt = 0; mt < 2; ++mt)
#pragma unroll
            for (int nt = 0; nt < 4; ++nt) sacc[mt][nt] = (f32x4){0.f, 0.f, 0.f, 0.f};
#pragma unroll
        for (int nt = 0; nt < 4; ++nt) {
            bf16x8 kf0 = *(const bf16x8*)&Ks[nt * 16 + l15][quad * 8];
            bf16x8 kf1 = *(const bf16x8*)&Ks[nt * 16 + l15][32 + quad * 8];
#pragma unroll
            for (int mt = 0; mt < 2; ++mt) {
                sacc[mt][nt] = __builtin_amdgcn_mfma_f32_16x16x32_bf16(qf[mt][0], kf0, sacc[mt][nt], 0, 0, 0);
                sacc[mt][nt] = __builtin_amdgcn_mfma_f32_16x16x32_bf16(qf[mt][1], kf1, sacc[mt][nt], 0, 0, 0);
            }
        }
        // sigmoid -> P (bf16, LDS round-trip to A-operand layout); rows wave-private
#pragma unroll
        for (int mt = 0; mt < 2; ++mt)
#pragma unroll
            for (int nt = 0; nt < 4; ++nt)
#pragma unroll
                for (int rr = 0; rr < 4; ++rr) {
                    float s = sacc[mt][nt][rr];
                    float z = __builtin_amdgcn_rcpf(
                        1.0f + __builtin_amdgcn_exp2f(s * -0.18033688011112042f));
                    Ps[w * 32 + mt * 16 + quad * 4 + rr][nt * 16 + l15] = f2bf(z);
                }
        __syncthreads();
        // O += P V
        bf16x8 vfr[2][4];
#pragma unroll
        for (int kc = 0; kc < 2; ++kc)
#pragma unroll
            for (int dt = 0; dt < 4; ++dt)
                vfr[kc][dt] = *(const bf16x8*)&Vt[dt * 16 + l15][kc * 32 + quad * 8];
#pragma unroll
        for (int mt = 0; mt < 2; ++mt)
#pragma unroll
            for (int kc = 0; kc < 2; ++kc) {
                bf16x8 pf = *(const bf16x8*)&Ps[w * 32 + mt * 16 + l15][kc * 32 + quad * 8];
#pragma unroll
                for (int dt = 0; dt < 4; ++dt)
                    oacc[mt][dt] = __builtin_amdgcn_mfma_f32_16x16x32_bf16(pf, vfr[kc][dt], oacc[mt][dt], 0, 0, 0);
            }
    }
#pragma unroll
    for (int mt = 0; mt < 2; ++mt)
#pragma unroll
        for (int dt = 0; dt < 4; ++dt)
#pragma unroll
            for (int rr = 0; rr < 4; ++rr) {
                int tok = q0 + w * 32 + mt * 16 + quad * 4 + rr;
                int c = h * 64 + dt * 16 + l15;
                o[((size_t)b * NTOK + tok) * CDIM + c] = f2bf(oacc[mt][dt][rr]);
            }
}

// ---------------- depthwise conv, register sliding window (fp32) ----------------
template<int K>
__global__ __launch_bounds__(256) void k_dwconv_t(
    const float* __restrict__ in, const float* __restrict__ w,
    const float* __restrict__ bias, float* __restrict__ out) {
    constexpr int PAD = K / 2;
    constexpr int KK = K * K;
    int t = threadIdx.x;
    int c = blockIdx.y * 64 + (t & 63);
    int j = blockIdx.x * 4 + (t >> 6);
    int b = blockIdx.z;
    float wr[KK];
#pragma unroll
    for (int qq = 0; qq < KK; ++qq) wr[qq] = w[(size_t)c * KK + qq];
    float bsv = bias[c];
    const float* base = in + (size_t)b * NTOK * CDIM + c;
    float win[K][K];
#pragma unroll
    for (int s = 1; s < K; ++s) {
        int ii = s - 1 - PAD;
#pragma unroll
        for (int qq = 0; qq < K; ++qq) {
            int jj = j - PAD + qq;
            win[s][qq] = (ii >= 0 && jj >= 0 && jj < 32)
                         ? base[(size_t)(ii * 32 + jj) * CDIM] : 0.0f;
        }
    }
#pragma unroll
    for (int i = 0; i < 32; ++i) {
#pragma unroll
        for (int r = 0; r < K - 1; ++r)
#pragma unroll
            for (int qq = 0; qq < K; ++qq) win[r][qq] = win[r + 1][qq];
        int ii = i + PAD;
#pragma unroll
        for (int qq = 0; qq < K; ++qq) {
            int jj = j - PAD + qq;
            win[K - 1][qq] = (ii < 32 && jj >= 0 && jj < 32)
                             ? base[(size_t)(ii * 32 + jj) * CDIM] : 0.0f;
        }
        float acc = bsv;
#pragma unroll
        for (int r = 0; r < K; ++r)
#pragma unroll
            for (int qq = 0; qq < K; ++qq)
                acc = fmaf(win[r][qq], wr[r * K + qq], acc);
        out[((size_t)b * NTOK + i * 32 + j) * CDIM + c] = acc;
    }
}

// ---------------- layernorm over C=768, nullable fp32/bf16 outputs ----------------
__global__ __launch_bounds__(256) void k_ln(
    const float* __restrict__ in, const float* __restrict__ g,
    const float* __restrict__ b, float* __restrict__ outF, short* __restrict__ outB) {
    int row = blockIdx.x;
    const float* xr = in + (size_t)row * CDIM;
    int t = threadIdx.x;
    float x0 = xr[t], x1 = xr[t + 256], x2 = xr[t + 512];
    float s = x0 + x1 + x2;
    float sq = x0 * x0 + x1 * x1 + x2 * x2;
#pragma unroll
    for (int off = 32; off > 0; off >>= 1) {
        s += __shfl_down(s, off);
        sq += __shfl_down(sq, off);
    }
    __shared__ float ws[4], wq2[4];
    int wid = t >> 6, lane = t & 63;
    if (lane == 0) { ws[wid] = s; wq2[wid] = sq; }
    __syncthreads();
    if (t == 0) {
        float S = ws[0] + ws[1] + ws[2] + ws[3];
        float Q = wq2[0] + wq2[1] + wq2[2] + wq2[3];
        float m = S * (1.0f / CDIM);
        float var = Q * (1.0f / CDIM) - m * m;
        ws[0] = m;
        wq2[0] = rsqrtf(var + 1e-5f);
    }
    __syncthreads();
    float m = ws[0], inv = wq2[0];
    float y0 = (x0 - m) * inv * g[t] + b[t];
    float y1 = (x1 - m) * inv * g[t + 256] + b[t + 256];
    float y2 = (x2 - m) * inv * g[t + 512] + b[t + 512];
    if (outF) {
        float* orow = outF + (size_t)row * CDIM;
        orow[t] = y0; orow[t + 256] = y1; orow[t + 512] = y2;
    }
    if (outB) {
        short* orow = outB + (size_t)row * CDIM;
        orow[t] = f2bf(y0); orow[t + 256] = f2bf(y1); orow[t + 512] = f2bf(y2);
    }
}

// ---------------- final combine + transpose back to [B,C,N] ----------------
__global__ void k_final(const float* __restrict__ y, const float* __restrict__ xln,
                        const float* __restrict__ scale, const float* __restrict__ alph,
                        float* __restrict__ out) {
    __shared__ float tile[32][33];
    int b = blockIdx.z, n0 = blockIdx.x * 32, c0 = blockIdx.y * 32;
    int tx = threadIdx.x, ty = threadIdx.y;
#pragma unroll
    for (int r = 0; r < 4; ++r) {
        int n = n0 + ty + r * 8, c = c0 + tx;
        size_t idx = ((size_t)b * NTOK + n) * CDIM + c;
        tile[tx][ty + r * 8] = scale[c] * y[idx] + alph[c] * xln[idx];
    }
    __syncthreads();
#pragma unroll
    for (int r = 0; r < 4; ++r) {
        int c = c0 + ty + r * 8;
        out[((size_t)b * CDIM + c) * NTOK + n0 + tx] = tile[ty + r * 8][tx];
    }
}

extern "C" void kernel_launch(void* const* d_in, const int* in_sizes, int n_in,
                              void* d_out, int out_size, void* d_ws, size_t ws_size,
                              hipStream_t stream) {
    const float* dec = (const float*)d_in[0];
    const float* wq1 = (const float*)d_in[1]; const float* bq1 = (const float*)d_in[2];
    const float* wk1 = (const float*)d_in[3]; const float* bk1 = (const float*)d_in[4];
    const float* wv1 = (const float*)d_in[5]; const float* bv1 = (const float*)d_in[6];
    const float* wo1 = (const float*)d_in[7]; const float* bo1 = (const float*)d_in[8];
    const float* wq2 = (const float*)d_in[9]; const float* bq2 = (const float*)d_in[10];
    const float* wk2 = (const float*)d_in[11]; const float* bk2 = (const float*)d_in[12];
    const float* wv2 = (const float*)d_in[13]; const float* bv2 = (const float*)d_in[14];
    const float* wo2 = (const float*)d_in[15]; const float* bo2 = (const float*)d_in[16];
    const float* alphas1 = (const float*)d_in[17];
    const float* alphas2 = (const float*)d_in[18];
    const float* peg_w = (const float*)d_in[19]; const float* peg_b = (const float*)d_in[20];
    const float* ln1_g = (const float*)d_in[21]; const float* ln1_b = (const float*)d_in[22];
    const float* ln2_g = (const float*)d_in[23]; const float* ln2_b = (const float*)d_in[24];
    const float* cn_dw_w = (const float*)d_in[25]; const float* cn_dw_b = (const float*)d_in[26];
    const float* cn_ln_g = (const float*)d_in[27]; const float* cn_ln_b = (const float*)d_in[28];
    const float* cn_w1 = (const float*)d_in[29]; const float* cn_b1 = (const float*)d_in[30];
    const float* cn_w2 = (const float*)d_in[31]; const float* cn_b2 = (const float*)d_in[32];
    const float* cn_scale = (const float*)d_in[33]; const float* cn_alphas = (const float*)d_in[34];
    float* out = (float*)d_out;

    const size_t S = (size_t)BATCH * NTOK * CDIM;  // 6291456
    float* A0 = (float*)d_ws;
    float* A1 = A0 + S;
    short* Xb  = (short*)(A1 + S);
    short* QKV = Xb + S;            // 3*S bf16 (q | k | v)
    short* Ob  = QKV + 3 * S;
    short* Hb  = Ob + S;            // 4096*3072 = 2*S bf16 (MLP hidden chunk)
    short* Wqkv1 = Hb + 2 * S;
    short* Wqkv2 = Wqkv1 + 2304 * 768;
    short* WoT1  = Wqkv2 + 2304 * 768;
    short* WoT2  = WoT1 + 768 * 768;
    short* W1T   = WoT2 + 768 * 768;
    short* W2T   = W1T + (size_t)3072 * 768;
    float* bqkv1 = (float*)(W2T + (size_t)768 * 3072);
    float* bqkv2 = bqkv1 + 2304;
    float* yF = (float*)QKV;        // aliases q/k/v region (dead after attention 2)

    dim3 tb(32, 8);
    dim3 dwgrid(8, 12, 8);

    // ---- weight prep (per-launch; ~30 us total) ----
    k_packqkv<<<dim3(12, 72), 256, 0, stream>>>(wq1, wk1, wv1, wq2, wk2, wv2, Wqkv1, Wqkv2);
    k_wtrans<<<dim3(24, 24), tb, 0, stream>>>(wo1, WoT1, 768, 768);
    k_wtrans<<<dim3(24, 24), tb, 0, stream>>>(wo2, WoT2, 768, 768);
    k_wtrans<<<dim3(96, 24), tb, 0, stream>>>(cn_w1, W1T, 768, 3072);
    k_wtrans<<<dim3(24, 96), tb, 0, stream>>>(cn_w2, W2T, 3072, 768);
    k_packbias<<<18, 256, 0, stream>>>(bq1, bk1, bv1, bq2, bk2, bv2, bqkv1, bqkv2);

    // ---- x = transpose(decoder), fp32 + bf16 ----
    k_transpose_in<<<dim3(32, 24, 8), tb, 0, stream>>>(dec, A0, Xb);

    // ---- block 1 ----
    k_gemm_mfma<GM_QKV><<<dim3(64, 18), 256, 0, stream>>>(
        Xb, Wqkv1, bqkv1, nullptr, nullptr, nullptr, QKV, 8192, 2304, 768);
    k_attn_mfma<<<dim3(8, 12, 8), 256, 0, stream>>>(QKV, QKV + S, QKV + 2 * S, Ob);
    k_gemm_mfma<GM_PROJ><<<dim3(64, 6), 256, 0, stream>>>(
        Ob, WoT1, bo1, A0, alphas1, A1, nullptr, 8192, 768, 768);
    k_dwconv_t<3><<<dwgrid, 256, 0, stream>>>(A1, peg_w, peg_b, A0);
    k_ln<<<8192, 256, 0, stream>>>(A0, ln1_g, ln1_b, A1, Xb);

    // ---- block 2 ----
    k_gemm_mfma<GM_QKV><<<dim3(64, 18), 256, 0, stream>>>(
        Xb, Wqkv2, bqkv2, nullptr, nullptr, nullptr, QKV, 8192, 2304, 768);
    k_attn_mfma<<<dim3(8, 12, 8), 256, 0, stream>>>(QKV, QKV + S, QKV + 2 * S, Ob);
    k_gemm_mfma<GM_PROJ><<<dim3(64, 6), 256, 0, stream>>>(
        Ob, WoT2, bo2, A1, alphas2, A0, nullptr, 8192, 768, 768);
    k_ln<<<8192, 256, 0, stream>>>(A0, ln2_g, ln2_b, A1, nullptr);  // A1 = xln2 (kept)

    // ---- CNBlock head ----
    k_dwconv_t<7><<<dwgrid, 256, 0, stream>>>(A1, cn_dw_w, cn_dw_b, A0);
    k_ln<<<8192, 256, 0, stream>>>(A0, cn_ln_g, cn_ln_b, nullptr, Xb);
    for (int ch = 0; ch < 2; ++ch) {
        const short* src = Xb + (size_t)ch * 4096 * CDIM;
        float* dst = yF + (size_t)ch * 4096 * CDIM;
        k_gemm_mfma<GM_GELU><<<dim3(32, 24), 256, 0, stream>>>(
            src, W1T, cn_b1, nullptr, nullptr, nullptr, Hb, 4096, 3072, 768);
        k_gemm_mfma<GM_PLAIN><<<dim3(32, 6), 256, 0, stream>>>(
            Hb, W2T, cn_b2, nullptr, nullptr, dst, nullptr, 4096, 768, 3072);
    }
    // ---- out = cn_scale*y + cn_alphas*xln2, transposed to [B,C,H,W] ----
    k_final<<<dim3(32, 24, 8), tb, 0, stream>>>(yF, A1, cn_scale, cn_alphas, out);
}

// Round 5
// 702.495 us; speedup vs baseline: 6.8648x; 1.1001x over previous
//
#include <hip/hip_runtime.h>
#include <math.h>

#define BATCH 8
#define CDIM 768
#define NTOK 1024
#define NH 12
#define HDIM 64

typedef __attribute__((ext_vector_type(8))) short bf16x8;
typedef __attribute__((ext_vector_type(4))) float f32x4;

__device__ inline short f2bf(float f) {
    union { float f; unsigned u; } v; v.f = f;
    unsigned r = (v.u + 0x7FFF + ((v.u >> 16) & 1)) >> 16;
    return (short)r;
}

// ---------------- transpose [B,C,N] -> [B,N,C], fp32 + bf16 mirror ----------------
__global__ void k_transpose_in(const float* __restrict__ dec, float* __restrict__ x,
                               short* __restrict__ xb) {
    __shared__ float tile[32][33];
    int b = blockIdx.z;
    int n0 = blockIdx.x * 32;
    int c0 = blockIdx.y * 32;
    int tx = threadIdx.x, ty = threadIdx.y;
#pragma unroll
    for (int r = 0; r < 4; ++r) {
        int c = c0 + ty + r * 8;
        tile[ty + r * 8][tx] = dec[((size_t)b * CDIM + c) * NTOK + n0 + tx];
    }
    __syncthreads();
#pragma unroll
    for (int r = 0; r < 4; ++r) {
        int n = n0 + ty + r * 8;
        float val = tile[tx][ty + r * 8];
        size_t idx = ((size_t)b * NTOK + n) * CDIM + c0 + tx;
        x[idx] = val;
        xb[idx] = f2bf(val);
    }
}

// ---------------- weight transpose fp32 [R,C] -> bf16 [C,R] ----------------
__global__ void k_wtrans(const float* __restrict__ src, short* __restrict__ dst,
                         int R, int C) {
    __shared__ float tile[32][33];
    int c0 = blockIdx.x * 32, r0 = blockIdx.y * 32;
    int tx = threadIdx.x, ty = threadIdx.y;
#pragma unroll
    for (int p = 0; p < 4; ++p)
        tile[ty + p * 8][tx] = src[(size_t)(r0 + ty + p * 8) * C + c0 + tx];
    __syncthreads();
#pragma unroll
    for (int p = 0; p < 4; ++p)
        dst[(size_t)(c0 + ty + p * 8) * R + r0 + tx] = f2bf(tile[tx][ty + p * 8]);
}

// ---------------- pack per-head qkv weights -> [2304,768] bf16 (n = sect*768+h*64+d) ----
__global__ __launch_bounds__(256) void k_packqkv(
    const float* __restrict__ wq1, const float* __restrict__ wk1, const float* __restrict__ wv1,
    const float* __restrict__ wq2, const float* __restrict__ wk2, const float* __restrict__ wv2,
    short* __restrict__ dst1, short* __restrict__ dst2) {
    __shared__ float tile[64][65];
    int z = blockIdx.y;                 // 0..71
    int set = z / 36, rem = z % 36, sect = rem / 12, h = rem % 12;
    const float* srcs[6] = {wq1, wk1, wv1, wq2, wk2, wv2};
    const float* src = srcs[set * 3 + sect] + (size_t)h * 768 * 64;
    short* dst = (set ? dst2 : dst1) + ((size_t)sect * 768 + h * 64) * 768;
    int k0 = blockIdx.x * 64;
    int t = threadIdx.x;
#pragma unroll
    for (int p = 0; p < 16; ++p) {
        int gid = t + p * 256;
        int r = gid >> 6, c = gid & 63;
        tile[r][c] = src[(size_t)(k0 + r) * 64 + c];
    }
    __syncthreads();
#pragma unroll
    for (int p = 0; p < 16; ++p) {
        int gid = t + p * 256;
        int d = gid >> 6, kk = gid & 63;
        dst[(size_t)d * 768 + k0 + kk] = f2bf(tile[kk][d]);
    }
}

__global__ void k_packbias(const float* __restrict__ bq1, const float* __restrict__ bk1,
                           const float* __restrict__ bv1, const float* __restrict__ bq2,
                           const float* __restrict__ bk2, const float* __restrict__ bv2,
                           float* __restrict__ d1, float* __restrict__ d2) {
    int tid = blockIdx.x * 256 + threadIdx.x;
    if (tid >= 4608) return;
    int set = tid / 2304, n = tid % 2304;
    int sect = n / 768, rem = n % 768;
    const float* srcs[6] = {bq1, bk1, bv1, bq2, bk2, bv2};
    float v = srcs[set * 3 + sect][rem];
    (set ? d2 : d1)[n] = v;
}

// ---------------- generic bf16 MFMA GEMM, 128xBN tile, BK=32 ----------------
// A [M,K] bf16 row-major; Bt [N,K] bf16 row-major (i.e. B transposed)
// K-loop structure identical to round-3 (proven stable across graph replays).
#define GM_PLAIN 0
#define GM_PROJ  1
#define GM_GELU  2
#define GM_QKV   3
#define QKVSEC ((size_t)BATCH * NH * NTOK * HDIM)  // 6291456

template<int MODE, int BN>
__global__ __launch_bounds__(256) void k_gemm_mfma(
    const short* __restrict__ A, const short* __restrict__ Bt,
    const float* __restrict__ bias, const float* __restrict__ resid,
    const float* __restrict__ rscale, float* __restrict__ outF,
    short* __restrict__ outB, int M, int N, int K) {
    constexpr int NT = BN / 32;   // 16-col tiles per wave
    constexpr int BP = BN / 64;   // B staging passes
    __shared__ short As[128][40];
    __shared__ short Bs[BN][40];
    int t = threadIdx.x;
    int w = t >> 6, lane = t & 63, l15 = lane & 15, quad = lane >> 4;
    int r0 = blockIdx.x * 128, n0 = blockIdx.y * BN;
    int wr = (w >> 1) * 64, wc = (w & 1) * (BN / 2);
    f32x4 acc[4][NT];
#pragma unroll
    for (int i = 0; i < 4; ++i)
#pragma unroll
        for (int j = 0; j < NT; ++j) acc[i][j] = (f32x4){0.f, 0.f, 0.f, 0.f};
    int sr = t >> 2, sc = (t & 3) * 8;
    for (int k0 = 0; k0 < K; k0 += 32) {
        __syncthreads();
#pragma unroll
        for (int p = 0; p < 2; ++p) {
            int r = sr + p * 64;
            *(bf16x8*)&As[r][sc] = *(const bf16x8*)&A[(size_t)(r0 + r) * K + k0 + sc];
        }
#pragma unroll
        for (int p = 0; p < BP; ++p) {
            int r = sr + p * 64;
            *(bf16x8*)&Bs[r][sc] = *(const bf16x8*)&Bt[(size_t)(n0 + r) * K + k0 + sc];
        }
        __syncthreads();
        bf16x8 af[4], bf[NT];
#pragma unroll
        for (int i = 0; i < 4; ++i) af[i] = *(const bf16x8*)&As[wr + i * 16 + l15][quad * 8];
#pragma unroll
        for (int j = 0; j < NT; ++j) bf[j] = *(const bf16x8*)&Bs[wc + j * 16 + l15][quad * 8];
#pragma unroll
        for (int i = 0; i < 4; ++i)
#pragma unroll
            for (int j = 0; j < NT; ++j)
                acc[i][j] = __builtin_amdgcn_mfma_f32_16x16x32_bf16(af[i], bf[j], acc[i][j], 0, 0, 0);
    }
#pragma unroll
    for (int i = 0; i < 4; ++i)
#pragma unroll
        for (int j = 0; j < NT; ++j)
#pragma unroll
            for (int rr = 0; rr < 4; ++rr) {
                int row = r0 + wr + i * 16 + quad * 4 + rr;
                int col = n0 + wc + j * 16 + l15;
                float val = acc[i][j][rr] + bias[col];
                if (MODE == GM_PROJ) {
                    val += rscale[col] * resid[(size_t)row * N + col];
                    outF[(size_t)row * N + col] = val;
                } else if (MODE == GM_GELU) {
                    val = 0.5f * val * (1.0f + erff(val * 0.70710678118f));
                    outB[(size_t)row * N + col] = f2bf(val);
                } else if (MODE == GM_PLAIN) {
                    outF[(size_t)row * N + col] = val;
                } else {  // GM_QKV: scatter into q/k/v [B,H,N,64]
                    int sect = col / 768, rem = col - sect * 768;
                    int hh = rem >> 6, d = rem & 63;
                    int bb = row >> 10, tok = row & 1023;
                    outB[(size_t)sect * QKVSEC +
                         (((size_t)bb * NH + hh) * NTOK + tok) * HDIM + d] = f2bf(val);
                }
            }
}

// ---------------- MFMA sigmoid attention ----------------
// per (b,h): O = sigmoid(QK^T/8) V ; q/k/v [B,H,N,64] bf16; O -> [B,N,C] bf16
__global__ __launch_bounds__(256) void k_attn_mfma(
    const short* __restrict__ q, const short* __restrict__ k,
    const short* __restrict__ v, short* __restrict__ o) {
    __shared__ short Ks[64][72];
    __shared__ short Vt[64][72];
    __shared__ short Ps[128][72];
    int b = blockIdx.z, h = blockIdx.y;
    int q0 = blockIdx.x * 128;
    int t = threadIdx.x;
    int w = t >> 6, lane = t & 63, l15 = lane & 15, quad = lane >> 4;
    size_t base = ((size_t)(b * NH + h)) * NTOK * HDIM;
    const short* qp = q + base;
    const short* kp = k + base;
    const short* vp = v + base;
    bf16x8 qf[2][2];
#pragma unroll
    for (int mt = 0; mt < 2; ++mt)
#pragma unroll
        for (int kc = 0; kc < 2; ++kc)
            qf[mt][kc] = *(const bf16x8*)&qp[(size_t)(q0 + w * 32 + mt * 16 + l15) * HDIM + kc * 32 + quad * 8];
    f32x4 oacc[2][4];
#pragma unroll
    for (int mt = 0; mt < 2; ++mt)
#pragma unroll
        for (int dt = 0; dt < 4; ++dt) oacc[mt][dt] = (f32x4){0.f, 0.f, 0.f, 0.f};
    for (int kt = 0; kt < 16; ++kt) {
        __syncthreads();
#pragma unroll
        for (int p = 0; p < 2; ++p) {
            int gid = t + p * 256;
            int r = gid >> 3, c8 = (gid & 7) * 8;
            *(bf16x8*)&Ks[r][c8] = *(const bf16x8*)&kp[(size_t)(kt * 64 + r) * HDIM + c8];
        }
#pragma unroll
        for (int p = 0; p < 2; ++p) {
            int tok = t & 63, d0 = (t >> 6) * 8 + p * 32;
            bf16x8 vv = *(const bf16x8*)&vp[(size_t)(kt * 64 + tok) * HDIM + d0];
#pragma unroll
            for (int j = 0; j < 8; ++j) Vt[d0 + j][tok] = vv[j];
        }
        __syncthreads();
        // S = Q K^T for this wave's 32 q-rows x 64 keys
        f32x4 sacc[2][4];
#pragma unroll
        for (int mt = 0; mt < 2; ++mt)
#pragma unroll
            for (int nt = 0; nt < 4; ++nt) sacc[mt][nt] = (f32x4){0.f, 0.f, 0.f, 0.f};
#pragma unroll
        for (int nt = 0; nt < 4; ++nt) {
            bf16x8 kf0 = *(const bf16x8*)&Ks[nt * 16 + l15][quad * 8];
            bf16x8 kf1 = *(const bf16x8*)&Ks[nt * 16 + l15][32 + quad * 8];
#pragma unroll
            for (int mt = 0; mt < 2; ++mt) {
                sacc[mt][nt] = __builtin_amdgcn_mfma_f32_16x16x32_bf16(qf[mt][0], kf0, sacc[mt][nt], 0, 0, 0);
                sacc[mt][nt] = __builtin_amdgcn_mfma_f32_16x16x32_bf16(qf[mt][1], kf1, sacc[mt][nt], 0, 0, 0);
            }
        }
        // sigmoid -> P (bf16, LDS round-trip to A-operand layout); rows wave-private
#pragma unroll
        for (int mt = 0; mt < 2; ++mt)
#pragma unroll
            for (int nt = 0; nt < 4; ++nt)
#pragma unroll
                for (int rr = 0; rr < 4; ++rr) {
                    float s = sacc[mt][nt][rr];
                    float z = __builtin_amdgcn_rcpf(
                        1.0f + __builtin_amdgcn_exp2f(s * -0.18033688011112042f));
                    Ps[w * 32 + mt * 16 + quad * 4 + rr][nt * 16 + l15] = f2bf(z);
                }
        __syncthreads();
        // O += P V
        bf16x8 vfr[2][4];
#pragma unroll
        for (int kc = 0; kc < 2; ++kc)
#pragma unroll
            for (int dt = 0; dt < 4; ++dt)
                vfr[kc][dt] = *(const bf16x8*)&Vt[dt * 16 + l15][kc * 32 + quad * 8];
#pragma unroll
        for (int mt = 0; mt < 2; ++mt)
#pragma unroll
            for (int kc = 0; kc < 2; ++kc) {
                bf16x8 pf = *(const bf16x8*)&Ps[w * 32 + mt * 16 + l15][kc * 32 + quad * 8];
#pragma unroll
                for (int dt = 0; dt < 4; ++dt)
                    oacc[mt][dt] = __builtin_amdgcn_mfma_f32_16x16x32_bf16(pf, vfr[kc][dt], oacc[mt][dt], 0, 0, 0);
            }
    }
#pragma unroll
    for (int mt = 0; mt < 2; ++mt)
#pragma unroll
        for (int dt = 0; dt < 4; ++dt)
#pragma unroll
            for (int rr = 0; rr < 4; ++rr) {
                int tok = q0 + w * 32 + mt * 16 + quad * 4 + rr;
                int c = h * 64 + dt * 16 + l15;
                o[((size_t)b * NTOK + tok) * CDIM + c] = f2bf(oacc[mt][dt][rr]);
            }
}

// ---------------- depthwise conv, register sliding window (fp32) ----------------
template<int K>
__global__ __launch_bounds__(256) void k_dwconv_t(
    const float* __restrict__ in, const float* __restrict__ w,
    const float* __restrict__ bias, float* __restrict__ out) {
    constexpr int PAD = K / 2;
    constexpr int KK = K * K;
    int t = threadIdx.x;
    int c = blockIdx.y * 64 + (t & 63);
    int j = blockIdx.x * 4 + (t >> 6);
    int b = blockIdx.z;
    float wr[KK];
#pragma unroll
    for (int qq = 0; qq < KK; ++qq) wr[qq] = w[(size_t)c * KK + qq];
    float bsv = bias[c];
    const float* base = in + (size_t)b * NTOK * CDIM + c;
    float win[K][K];
#pragma unroll
    for (int s = 1; s < K; ++s) {
        int ii = s - 1 - PAD;
#pragma unroll
        for (int qq = 0; qq < K; ++qq) {
            int jj = j - PAD + qq;
            win[s][qq] = (ii >= 0 && jj >= 0 && jj < 32)
                         ? base[(size_t)(ii * 32 + jj) * CDIM] : 0.0f;
        }
    }
#pragma unroll
    for (int i = 0; i < 32; ++i) {
#pragma unroll
        for (int r = 0; r < K - 1; ++r)
#pragma unroll
            for (int qq = 0; qq < K; ++qq) win[r][qq] = win[r + 1][qq];
        int ii = i + PAD;
#pragma unroll
        for (int qq = 0; qq < K; ++qq) {
            int jj = j - PAD + qq;
            win[K - 1][qq] = (ii < 32 && jj >= 0 && jj < 32)
                             ? base[(size_t)(ii * 32 + jj) * CDIM] : 0.0f;
        }
        float acc = bsv;
#pragma unroll
        for (int r = 0; r < K; ++r)
#pragma unroll
            for (int qq = 0; qq < K; ++qq)
                acc = fmaf(win[r][qq], wr[r * K + qq], acc);
        out[((size_t)b * NTOK + i * 32 + j) * CDIM + c] = acc;
    }
}

// ---------------- layernorm over C=768, nullable fp32/bf16 outputs ----------------
__global__ __launch_bounds__(256) void k_ln(
    const float* __restrict__ in, const float* __restrict__ g,
    const float* __restrict__ b, float* __restrict__ outF, short* __restrict__ outB) {
    int row = blockIdx.x;
    const float* xr = in + (size_t)row * CDIM;
    int t = threadIdx.x;
    float x0 = xr[t], x1 = xr[t + 256], x2 = xr[t + 512];
    float s = x0 + x1 + x2;
    float sq = x0 * x0 + x1 * x1 + x2 * x2;
#pragma unroll
    for (int off = 32; off > 0; off >>= 1) {
        s += __shfl_down(s, off);
        sq += __shfl_down(sq, off);
    }
    __shared__ float ws[4], wq2[4];
    int wid = t >> 6, lane = t & 63;
    if (lane == 0) { ws[wid] = s; wq2[wid] = sq; }
    __syncthreads();
    if (t == 0) {
        float S = ws[0] + ws[1] + ws[2] + ws[3];
        float Q = wq2[0] + wq2[1] + wq2[2] + wq2[3];
        float m = S * (1.0f / CDIM);
        float var = Q * (1.0f / CDIM) - m * m;
        ws[0] = m;
        wq2[0] = rsqrtf(var + 1e-5f);
    }
    __syncthreads();
    float m = ws[0], inv = wq2[0];
    float y0 = (x0 - m) * inv * g[t] + b[t];
    float y1 = (x1 - m) * inv * g[t + 256] + b[t + 256];
    float y2 = (x2 - m) * inv * g[t + 512] + b[t + 512];
    if (outF) {
        float* orow = outF + (size_t)row * CDIM;
        orow[t] = y0; orow[t + 256] = y1; orow[t + 512] = y2;
    }
    if (outB) {
        short* orow = outB + (size_t)row * CDIM;
        orow[t] = f2bf(y0); orow[t + 256] = f2bf(y1); orow[t + 512] = f2bf(y2);
    }
}

// ---------------- final combine + transpose back to [B,C,N] ----------------
__global__ void k_final(const float* __restrict__ y, const float* __restrict__ xln,
                        const float* __restrict__ scale, const float* __restrict__ alph,
                        float* __restrict__ out) {
    __shared__ float tile[32][33];
    int b = blockIdx.z, n0 = blockIdx.x * 32, c0 = blockIdx.y * 32;
    int tx = threadIdx.x, ty = threadIdx.y;
#pragma unroll
    for (int r = 0; r < 4; ++r) {
        int n = n0 + ty + r * 8, c = c0 + tx;
        size_t idx = ((size_t)b * NTOK + n) * CDIM + c;
        tile[tx][ty + r * 8] = scale[c] * y[idx] + alph[c] * xln[idx];
    }
    __syncthreads();
#pragma unroll
    for (int r = 0; r < 4; ++r) {
        int c = c0 + ty + r * 8;
        out[((size_t)b * CDIM + c) * NTOK + n0 + tx] = tile[ty + r * 8][tx];
    }
}

extern "C" void kernel_launch(void* const* d_in, const int* in_sizes, int n_in,
                              void* d_out, int out_size, void* d_ws, size_t ws_size,
                              hipStream_t stream) {
    const float* dec = (const float*)d_in[0];
    const float* wq1 = (const float*)d_in[1]; const float* bq1 = (const float*)d_in[2];
    const float* wk1 = (const float*)d_in[3]; const float* bk1 = (const float*)d_in[4];
    const float* wv1 = (const float*)d_in[5]; const float* bv1 = (const float*)d_in[6];
    const float* wo1 = (const float*)d_in[7]; const float* bo1 = (const float*)d_in[8];
    const float* wq2 = (const float*)d_in[9]; const float* bq2 = (const float*)d_in[10];
    const float* wk2 = (const float*)d_in[11]; const float* bk2 = (const float*)d_in[12];
    const float* wv2 = (const float*)d_in[13]; const float* bv2 = (const float*)d_in[14];
    const float* wo2 = (const float*)d_in[15]; const float* bo2 = (const float*)d_in[16];
    const float* alphas1 = (const float*)d_in[17];
    const float* alphas2 = (const float*)d_in[18];
    const float* peg_w = (const float*)d_in[19]; const float* peg_b = (const float*)d_in[20];
    const float* ln1_g = (const float*)d_in[21]; const float* ln1_b = (const float*)d_in[22];
    const float* ln2_g = (const float*)d_in[23]; const float* ln2_b = (const float*)d_in[24];
    const float* cn_dw_w = (const float*)d_in[25]; const float* cn_dw_b = (const float*)d_in[26];
    const float* cn_ln_g = (const float*)d_in[27]; const float* cn_ln_b = (const float*)d_in[28];
    const float* cn_w1 = (const float*)d_in[29]; const float* cn_b1 = (const float*)d_in[30];
    const float* cn_w2 = (const float*)d_in[31]; const float* cn_b2 = (const float*)d_in[32];
    const float* cn_scale = (const float*)d_in[33]; const float* cn_alphas = (const float*)d_in[34];
    float* out = (float*)d_out;

    const size_t S = (size_t)BATCH * NTOK * CDIM;  // 6291456
    float* A0 = (float*)d_ws;
    float* A1 = A0 + S;
    short* Xb  = (short*)(A1 + S);
    short* QKV = Xb + S;            // 3*S bf16 (q | k | v)
    short* Ob  = QKV + 3 * S;
    short* Hb  = Ob + S;            // 2*S bf16
    short* Wqkv1 = Hb + 2 * S;
    short* Wqkv2 = Wqkv1 + 2304 * 768;
    short* WoT1  = Wqkv2 + 2304 * 768;
    short* WoT2  = WoT1 + 768 * 768;
    short* W1T   = WoT2 + 768 * 768;
    short* W2T   = W1T + (size_t)3072 * 768;
    float* bqkv1 = (float*)(W2T + (size_t)768 * 3072);
    float* bqkv2 = bqkv1 + 2304;
    // MLP-time aliases (QKV/Ob/Hb regions are dead by then):
    float* yF    = (float*)QKV;     // 8192x768 fp32 = first 2S shorts of QKV
    short* Hfull = QKV + 2 * S;     // 8192x3072 bf16 = 4S shorts (rest of QKV + Ob + Hb)

    dim3 tb(32, 8);
    dim3 dwgrid(8, 12, 8);

    // ---- weight prep (per-launch; ~30 us total) ----
    k_packqkv<<<dim3(12, 72), 256, 0, stream>>>(wq1, wk1, wv1, wq2, wk2, wv2, Wqkv1, Wqkv2);
    k_wtrans<<<dim3(24, 24), tb, 0, stream>>>(wo1, WoT1, 768, 768);
    k_wtrans<<<dim3(24, 24), tb, 0, stream>>>(wo2, WoT2, 768, 768);
    k_wtrans<<<dim3(96, 24), tb, 0, stream>>>(cn_w1, W1T, 768, 3072);
    k_wtrans<<<dim3(24, 96), tb, 0, stream>>>(cn_w2, W2T, 3072, 768);
    k_packbias<<<18, 256, 0, stream>>>(bq1, bk1, bv1, bq2, bk2, bv2, bqkv1, bqkv2);

    // ---- x = transpose(decoder), fp32 + bf16 ----
    k_transpose_in<<<dim3(32, 24, 8), tb, 0, stream>>>(dec, A0, Xb);

    // ---- block 1 ----
    k_gemm_mfma<GM_QKV, 128><<<dim3(64, 18), 256, 0, stream>>>(
        Xb, Wqkv1, bqkv1, nullptr, nullptr, nullptr, QKV, 8192, 2304, 768);
    k_attn_mfma<<<dim3(8, 12, 8), 256, 0, stream>>>(QKV, QKV + S, QKV + 2 * S, Ob);
    k_gemm_mfma<GM_PROJ, 64><<<dim3(64, 12), 256, 0, stream>>>(
        Ob, WoT1, bo1, A0, alphas1, A1, nullptr, 8192, 768, 768);
    k_dwconv_t<3><<<dwgrid, 256, 0, stream>>>(A1, peg_w, peg_b, A0);
    k_ln<<<8192, 256, 0, stream>>>(A0, ln1_g, ln1_b, A1, Xb);

    // ---- block 2 ----
    k_gemm_mfma<GM_QKV, 128><<<dim3(64, 18), 256, 0, stream>>>(
        Xb, Wqkv2, bqkv2, nullptr, nullptr, nullptr, QKV, 8192, 2304, 768);
    k_attn_mfma<<<dim3(8, 12, 8), 256, 0, stream>>>(QKV, QKV + S, QKV + 2 * S, Ob);
    k_gemm_mfma<GM_PROJ, 64><<<dim3(64, 12), 256, 0, stream>>>(
        Ob, WoT2, bo2, A1, alphas2, A0, nullptr, 8192, 768, 768);
    k_ln<<<8192, 256, 0, stream>>>(A0, ln2_g, ln2_b, A1, nullptr);  // A1 = xln2 (kept)

    // ---- CNBlock head ----
    k_dwconv_t<7><<<dwgrid, 256, 0, stream>>>(A1, cn_dw_w, cn_dw_b, A0);
    k_ln<<<8192, 256, 0, stream>>>(A0, cn_ln_g, cn_ln_b, nullptr, Xb);
    // MLP, full M=8192 (Hfull aliases dead QKV-tail/Ob/Hb; yF aliases QKV head)
    k_gemm_mfma<GM_GELU, 128><<<dim3(64, 24), 256, 0, stream>>>(
        Xb, W1T, cn_b1, nullptr, nullptr, nullptr, Hfull, 8192, 3072, 768);
    k_gemm_mfma<GM_PLAIN, 64><<<dim3(64, 12), 256, 0, stream>>>(
        Hfull, W2T, cn_b2, nullptr, nullptr, yF, nullptr, 8192, 768, 3072);
    // ---- out = cn_scale*y + cn_alphas*xln2, transposed to [B,C,H,W] ----
    k_final<<<dim3(32, 24, 8), tb, 0, stream>>>(yF, A1, cn_scale, cn_alphas, out);
}

// Round 6
// 685.451 us; speedup vs baseline: 7.0355x; 1.0249x over previous
//
#include <hip/hip_runtime.h>
#include <math.h>

#define BATCH 8
#define CDIM 768
#define NTOK 1024
#define NH 12
#define HDIM 64

typedef __attribute__((ext_vector_type(8))) short bf16x8;
typedef __attribute__((ext_vector_type(4))) float f32x4;

__device__ inline short f2bf(float f) {
    union { float f; unsigned u; } v; v.f = f;
    unsigned r = (v.u + 0x7FFF + ((v.u >> 16) & 1)) >> 16;
    return (short)r;
}

// async global->LDS DMA, 16 B per lane; lptr must be the WAVE-uniform base,
// lane l writes lptr + l*16 bytes (m97 pattern).
__device__ inline void async_copy16(const short* g, short* l) {
    __builtin_amdgcn_global_load_lds(
        (const __attribute__((address_space(1))) void*)g,
        (__attribute__((address_space(3))) void*)l, 16, 0, 0);
}

// ---------------- transpose [B,C,N] -> [B,N,C], fp32 + bf16 mirror ----------------
__global__ void k_transpose_in(const float* __restrict__ dec, float* __restrict__ x,
                               short* __restrict__ xb) {
    __shared__ float tile[32][33];
    int b = blockIdx.z;
    int n0 = blockIdx.x * 32;
    int c0 = blockIdx.y * 32;
    int tx = threadIdx.x, ty = threadIdx.y;
#pragma unroll
    for (int r = 0; r < 4; ++r) {
        int c = c0 + ty + r * 8;
        tile[ty + r * 8][tx] = dec[((size_t)b * CDIM + c) * NTOK + n0 + tx];
    }
    __syncthreads();
#pragma unroll
    for (int r = 0; r < 4; ++r) {
        int n = n0 + ty + r * 8;
        float val = tile[tx][ty + r * 8];
        size_t idx = ((size_t)b * NTOK + n) * CDIM + c0 + tx;
        x[idx] = val;
        xb[idx] = f2bf(val);
    }
}

// ---------------- weight transpose fp32 [R,C] -> bf16 [C,R] ----------------
__global__ void k_wtrans(const float* __restrict__ src, short* __restrict__ dst,
                         int R, int C) {
    __shared__ float tile[32][33];
    int c0 = blockIdx.x * 32, r0 = blockIdx.y * 32;
    int tx = threadIdx.x, ty = threadIdx.y;
#pragma unroll
    for (int p = 0; p < 4; ++p)
        tile[ty + p * 8][tx] = src[(size_t)(r0 + ty + p * 8) * C + c0 + tx];
    __syncthreads();
#pragma unroll
    for (int p = 0; p < 4; ++p)
        dst[(size_t)(c0 + ty + p * 8) * R + r0 + tx] = f2bf(tile[tx][ty + p * 8]);
}

// ---------------- pack per-head qkv weights -> [2304,768] bf16 (n = sect*768+h*64+d) ----
__global__ __launch_bounds__(256) void k_packqkv(
    const float* __restrict__ wq1, const float* __restrict__ wk1, const float* __restrict__ wv1,
    const float* __restrict__ wq2, const float* __restrict__ wk2, const float* __restrict__ wv2,
    short* __restrict__ dst1, short* __restrict__ dst2) {
    __shared__ float tile[64][65];
    int z = blockIdx.y;                 // 0..71
    int set = z / 36, rem = z % 36, sect = rem / 12, h = rem % 12;
    const float* srcs[6] = {wq1, wk1, wv1, wq2, wk2, wv2};
    const float* src = srcs[set * 3 + sect] + (size_t)h * 768 * 64;
    short* dst = (set ? dst2 : dst1) + ((size_t)sect * 768 + h * 64) * 768;
    int k0 = blockIdx.x * 64;
    int t = threadIdx.x;
#pragma unroll
    for (int p = 0; p < 16; ++p) {
        int gid = t + p * 256;
        int r = gid >> 6, c = gid & 63;
        tile[r][c] = src[(size_t)(k0 + r) * 64 + c];
    }
    __syncthreads();
#pragma unroll
    for (int p = 0; p < 16; ++p) {
        int gid = t + p * 256;
        int d = gid >> 6, kk = gid & 63;
        dst[(size_t)d * 768 + k0 + kk] = f2bf(tile[kk][d]);
    }
}

__global__ void k_packbias(const float* __restrict__ bq1, const float* __restrict__ bk1,
                           const float* __restrict__ bv1, const float* __restrict__ bq2,
                           const float* __restrict__ bk2, const float* __restrict__ bv2,
                           float* __restrict__ d1, float* __restrict__ d2) {
    int tid = blockIdx.x * 256 + threadIdx.x;
    if (tid >= 4608) return;
    int set = tid / 2304, n = tid % 2304;
    int sect = n / 768, rem = n % 768;
    const float* srcs[6] = {bq1, bk1, bv1, bq2, bk2, bv2};
    float v = srcs[set * 3 + sect][rem];
    (set ? d2 : d1)[n] = v;
}

// ---------------- generic bf16 MFMA GEMM, 128xBN tile, BK=32, global_load_lds ----------------
// A [M,K] bf16 row-major; Bt [N,K] bf16 row-major (i.e. B transposed)
// Unpadded LDS tiles (lane-contiguous: thread t's staging slot = t*16 B) so the
// wave-uniform-base + lane*16 DMA constraint holds. 2-barrier K-loop (m97 shape).
#define GM_PLAIN 0
#define GM_PROJ  1
#define GM_GELU  2
#define GM_QKV   3
#define QKVSEC ((size_t)BATCH * NH * NTOK * HDIM)  // 6291456

template<int MODE, int BN>
__global__ __launch_bounds__(256) void k_gemm_mfma(
    const short* __restrict__ A, const short* __restrict__ Bt,
    const float* __restrict__ bias, const float* __restrict__ resid,
    const float* __restrict__ rscale, float* __restrict__ outF,
    short* __restrict__ outB, int M, int N, int K) {
    constexpr int NT = BN / 32;   // 16-col tiles per wave
    constexpr int BP = BN / 64;   // B staging passes
    __shared__ short As[128 * 32];
    __shared__ short Bs[BN * 32];
    int t = threadIdx.x;
    int w = t >> 6, lane = t & 63, l15 = lane & 15, quad = lane >> 4;
    int r0 = blockIdx.x * 128, n0 = blockIdx.y * BN;
    int wr = (w >> 1) * 64, wc = (w & 1) * (BN / 2);
    f32x4 acc[4][NT];
#pragma unroll
    for (int i = 0; i < 4; ++i)
#pragma unroll
        for (int j = 0; j < NT; ++j) acc[i][j] = (f32x4){0.f, 0.f, 0.f, 0.f};
    int sr = t >> 2, sc = (t & 3) * 8;
    const short* Ag = A + (size_t)(r0 + sr) * K + sc;
    const short* Bg = Bt + (size_t)(n0 + sr) * K + sc;
    short* AsW = As + w * 512;   // wave-uniform base: lane l -> + l*8 shorts (16 B)
    short* BsW = Bs + w * 512;
    for (int k0 = 0; k0 < K; k0 += 32) {
        __syncthreads();
#pragma unroll
        for (int p = 0; p < 2; ++p)
            async_copy16(Ag + k0 + (size_t)p * 64 * K, AsW + p * 2048);
#pragma unroll
        for (int p = 0; p < BP; ++p)
            async_copy16(Bg + k0 + (size_t)p * 64 * K, BsW + p * 2048);
        __syncthreads();   // drains vmcnt(0): DMA complete for all waves
        bf16x8 af[4], bf[NT];
#pragma unroll
        for (int i = 0; i < 4; ++i)
            af[i] = *(const bf16x8*)&As[(wr + i * 16 + l15) * 32 + quad * 8];
#pragma unroll
        for (int j = 0; j < NT; ++j)
            bf[j] = *(const bf16x8*)&Bs[(wc + j * 16 + l15) * 32 + quad * 8];
#pragma unroll
        for (int i = 0; i < 4; ++i)
#pragma unroll
            for (int j = 0; j < NT; ++j)
                acc[i][j] = __builtin_amdgcn_mfma_f32_16x16x32_bf16(af[i], bf[j], acc[i][j], 0, 0, 0);
    }
#pragma unroll
    for (int i = 0; i < 4; ++i)
#pragma unroll
        for (int j = 0; j < NT; ++j)
#pragma unroll
            for (int rr = 0; rr < 4; ++rr) {
                int row = r0 + wr + i * 16 + quad * 4 + rr;
                int col = n0 + wc + j * 16 + l15;
                float val = acc[i][j][rr] + bias[col];
                if (MODE == GM_PROJ) {
                    val += rscale[col] * resid[(size_t)row * N + col];
                    outF[(size_t)row * N + col] = val;
                } else if (MODE == GM_GELU) {
                    val = 0.5f * val * (1.0f + erff(val * 0.70710678118f));
                    outB[(size_t)row * N + col] = f2bf(val);
                } else if (MODE == GM_PLAIN) {
                    outF[(size_t)row * N + col] = val;
                } else {  // GM_QKV: scatter into q/k/v [B,H,N,64]
                    int sect = col / 768, rem = col - sect * 768;
                    int hh = rem >> 6, d = rem & 63;
                    int bb = row >> 10, tok = row & 1023;
                    outB[(size_t)sect * QKVSEC +
                         (((size_t)bb * NH + hh) * NTOK + tok) * HDIM + d] = f2bf(val);
                }
            }
}

// ---------------- MFMA sigmoid attention ----------------
// per (b,h): O = sigmoid(QK^T/8) V ; q/k/v [B,H,N,64] bf16; O -> [B,N,C] bf16
__global__ __launch_bounds__(256) void k_attn_mfma(
    const short* __restrict__ q, const short* __restrict__ k,
    const short* __restrict__ v, short* __restrict__ o) {
    __shared__ short Ks[64][72];
    __shared__ short Vt[64][72];
    __shared__ short Ps[128][72];
    int b = blockIdx.z, h = blockIdx.y;
    int q0 = blockIdx.x * 128;
    int t = threadIdx.x;
    int w = t >> 6, lane = t & 63, l15 = lane & 15, quad = lane >> 4;
    size_t base = ((size_t)(b * NH + h)) * NTOK * HDIM;
    const short* qp = q + base;
    const short* kp = k + base;
    const short* vp = v + base;
    bf16x8 qf[2][2];
#pragma unroll
    for (int mt = 0; mt < 2; ++mt)
#pragma unroll
        for (int kc = 0; kc < 2; ++kc)
            qf[mt][kc] = *(const bf16x8*)&qp[(size_t)(q0 + w * 32 + mt * 16 + l15) * HDIM + kc * 32 + quad * 8];
    f32x4 oacc[2][4];
#pragma unroll
    for (int mt = 0; mt < 2; ++mt)
#pragma unroll
        for (int dt = 0; dt < 4; ++dt) oacc[mt][dt] = (f32x4){0.f, 0.f, 0.f, 0.f};
    for (int kt = 0; kt < 16; ++kt) {
        __syncthreads();
#pragma unroll
        for (int p = 0; p < 2; ++p) {
            int gid = t + p * 256;
            int r = gid >> 3, c8 = (gid & 7) * 8;
            *(bf16x8*)&Ks[r][c8] = *(const bf16x8*)&kp[(size_t)(kt * 64 + r) * HDIM + c8];
        }
#pragma unroll
        for (int p = 0; p < 2; ++p) {
            int tok = t & 63, d0 = (t >> 6) * 8 + p * 32;
            bf16x8 vv = *(const bf16x8*)&vp[(size_t)(kt * 64 + tok) * HDIM + d0];
#pragma unroll
            for (int j = 0; j < 8; ++j) Vt[d0 + j][tok] = vv[j];
        }
        __syncthreads();
        // S = Q K^T for this wave's 32 q-rows x 64 keys
        f32x4 sacc[2][4];
#pragma unroll
        for (int mt = 0; mt < 2; ++mt)
#pragma unroll
            for (int nt = 0; nt < 4; ++nt) sacc[mt][nt] = (f32x4){0.f, 0.f, 0.f, 0.f};
#pragma unroll
        for (int nt = 0; nt < 4; ++nt) {
            bf16x8 kf0 = *(const bf16x8*)&Ks[nt * 16 + l15][quad * 8];
            bf16x8 kf1 = *(const bf16x8*)&Ks[nt * 16 + l15][32 + quad * 8];
#pragma unroll
            for (int mt = 0; mt < 2; ++mt) {
                sacc[mt][nt] = __builtin_amdgcn_mfma_f32_16x16x32_bf16(qf[mt][0], kf0, sacc[mt][nt], 0, 0, 0);
                sacc[mt][nt] = __builtin_amdgcn_mfma_f32_16x16x32_bf16(qf[mt][1], kf1, sacc[mt][nt], 0, 0, 0);
            }
        }
        // sigmoid -> P (bf16, LDS round-trip to A-operand layout); rows wave-private
#pragma unroll
        for (int mt = 0; mt < 2; ++mt)
#pragma unroll
            for (int nt = 0; nt < 4; ++nt)
#pragma unroll
                for (int rr = 0; rr < 4; ++rr) {
                    float s = sacc[mt][nt][rr];
                    float z = __builtin_amdgcn_rcpf(
                        1.0f + __builtin_amdgcn_exp2f(s * -0.18033688011112042f));
                    Ps[w * 32 + mt * 16 + quad * 4 + rr][nt * 16 + l15] = f2bf(z);
                }
        __syncthreads();
        // O += P V
        bf16x8 vfr[2][4];
#pragma unroll
        for (int kc = 0; kc < 2; ++kc)
#pragma unroll
            for (int dt = 0; dt < 4; ++dt)
                vfr[kc][dt] = *(const bf16x8*)&Vt[dt * 16 + l15][kc * 32 + quad * 8];
#pragma unroll
        for (int mt = 0; mt < 2; ++mt)
#pragma unroll
            for (int kc = 0; kc < 2; ++kc) {
                bf16x8 pf = *(const bf16x8*)&Ps[w * 32 + mt * 16 + l15][kc * 32 + quad * 8];
#pragma unroll
                for (int dt = 0; dt < 4; ++dt)
                    oacc[mt][dt] = __builtin_amdgcn_mfma_f32_16x16x32_bf16(pf, vfr[kc][dt], oacc[mt][dt], 0, 0, 0);
            }
    }
#pragma unroll
    for (int mt = 0; mt < 2; ++mt)
#pragma unroll
        for (int dt = 0; dt < 4; ++dt)
#pragma unroll
            for (int rr = 0; rr < 4; ++rr) {
                int tok = q0 + w * 32 + mt * 16 + quad * 4 + rr;
                int c = h * 64 + dt * 16 + l15;
                o[((size_t)b * NTOK + tok) * CDIM + c] = f2bf(oacc[mt][dt][rr]);
            }
}

// ---------------- depthwise conv, register sliding window (fp32) ----------------
template<int K>
__global__ __launch_bounds__(256) void k_dwconv_t(
    const float* __restrict__ in, const float* __restrict__ w,
    const float* __restrict__ bias, float* __restrict__ out) {
    constexpr int PAD = K / 2;
    constexpr int KK = K * K;
    int t = threadIdx.x;
    int c = blockIdx.y * 64 + (t & 63);
    int j = blockIdx.x * 4 + (t >> 6);
    int b = blockIdx.z;
    float wr[KK];
#pragma unroll
    for (int qq = 0; qq < KK; ++qq) wr[qq] = w[(size_t)c * KK + qq];
    float bsv = bias[c];
    const float* base = in + (size_t)b * NTOK * CDIM + c;
    float win[K][K];
#pragma unroll
    for (int s = 1; s < K; ++s) {
        int ii = s - 1 - PAD;
#pragma unroll
        for (int qq = 0; qq < K; ++qq) {
            int jj = j - PAD + qq;
            win[s][qq] = (ii >= 0 && jj >= 0 && jj < 32)
                         ? base[(size_t)(ii * 32 + jj) * CDIM] : 0.0f;
        }
    }
#pragma unroll
    for (int i = 0; i < 32; ++i) {
#pragma unroll
        for (int r = 0; r < K - 1; ++r)
#pragma unroll
            for (int qq = 0; qq < K; ++qq) win[r][qq] = win[r + 1][qq];
        int ii = i + PAD;
#pragma unroll
        for (int qq = 0; qq < K; ++qq) {
            int jj = j - PAD + qq;
            win[K - 1][qq] = (ii < 32 && jj >= 0 && jj < 32)
                             ? base[(size_t)(ii * 32 + jj) * CDIM] : 0.0f;
        }
        float acc = bsv;
#pragma unroll
        for (int r = 0; r < K; ++r)
#pragma unroll
            for (int qq = 0; qq < K; ++qq)
                acc = fmaf(win[r][qq], wr[r * K + qq], acc);
        out[((size_t)b * NTOK + i * 32 + j) * CDIM + c] = acc;
    }
}

// ---------------- layernorm over C=768, nullable fp32/bf16 outputs ----------------
__global__ __launch_bounds__(256) void k_ln(
    const float* __restrict__ in, const float* __restrict__ g,
    const float* __restrict__ b, float* __restrict__ outF, short* __restrict__ outB) {
    int row = blockIdx.x;
    const float* xr = in + (size_t)row * CDIM;
    int t = threadIdx.x;
    float x0 = xr[t], x1 = xr[t + 256], x2 = xr[t + 512];
    float s = x0 + x1 + x2;
    float sq = x0 * x0 + x1 * x1 + x2 * x2;
#pragma unroll
    for (int off = 32; off > 0; off >>= 1) {
        s += __shfl_down(s, off);
        sq += __shfl_down(sq, off);
    }
    __shared__ float ws[4], wq2[4];
    int wid = t >> 6, lane = t & 63;
    if (lane == 0) { ws[wid] = s; wq2[wid] = sq; }
    __syncthreads();
    if (t == 0) {
        float S = ws[0] + ws[1] + ws[2] + ws[3];
        float Q = wq2[0] + wq2[1] + wq2[2] + wq2[3];
        float m = S * (1.0f / CDIM);
        float var = Q * (1.0f / CDIM) - m * m;
        ws[0] = m;
        wq2[0] = rsqrtf(var + 1e-5f);
    }
    __syncthreads();
    float m = ws[0], inv = wq2[0];
    float y0 = (x0 - m) * inv * g[t] + b[t];
    float y1 = (x1 - m) * inv * g[t + 256] + b[t + 256];
    float y2 = (x2 - m) * inv * g[t + 512] + b[t + 512];
    if (outF) {
        float* orow = outF + (size_t)row * CDIM;
        orow[t] = y0; orow[t + 256] = y1; orow[t + 512] = y2;
    }
    if (outB) {
        short* orow = outB + (size_t)row * CDIM;
        orow[t] = f2bf(y0); orow[t + 256] = f2bf(y1); orow[t + 512] = f2bf(y2);
    }
}

// ---------------- final combine + transpose back to [B,C,N] ----------------
__global__ void k_final(const float* __restrict__ y, const float* __restrict__ xln,
                        const float* __restrict__ scale, const float* __restrict__ alph,
                        float* __restrict__ out) {
    __shared__ float tile[32][33];
    int b = blockIdx.z, n0 = blockIdx.x * 32, c0 = blockIdx.y * 32;
    int tx = threadIdx.x, ty = threadIdx.y;
#pragma unroll
    for (int r = 0; r < 4; ++r) {
        int n = n0 + ty + r * 8, c = c0 + tx;
        size_t idx = ((size_t)b * NTOK + n) * CDIM + c;
        tile[tx][ty + r * 8] = scale[c] * y[idx] + alph[c] * xln[idx];
    }
    __syncthreads();
#pragma unroll
    for (int r = 0; r < 4; ++r) {
        int c = c0 + ty + r * 8;
        out[((size_t)b * CDIM + c) * NTOK + n0 + tx] = tile[ty + r * 8][tx];
    }
}

extern "C" void kernel_launch(void* const* d_in, const int* in_sizes, int n_in,
                              void* d_out, int out_size, void* d_ws, size_t ws_size,
                              hipStream_t stream) {
    const float* dec = (const float*)d_in[0];
    const float* wq1 = (const float*)d_in[1]; const float* bq1 = (const float*)d_in[2];
    const float* wk1 = (const float*)d_in[3]; const float* bk1 = (const float*)d_in[4];
    const float* wv1 = (const float*)d_in[5]; const float* bv1 = (const float*)d_in[6];
    const float* wo1 = (const float*)d_in[7]; const float* bo1 = (const float*)d_in[8];
    const float* wq2 = (const float*)d_in[9]; const float* bq2 = (const float*)d_in[10];
    const float* wk2 = (const float*)d_in[11]; const float* bk2 = (const float*)d_in[12];
    const float* wv2 = (const float*)d_in[13]; const float* bv2 = (const float*)d_in[14];
    const float* wo2 = (const float*)d_in[15]; const float* bo2 = (const float*)d_in[16];
    const float* alphas1 = (const float*)d_in[17];
    const float* alphas2 = (const float*)d_in[18];
    const float* peg_w = (const float*)d_in[19]; const float* peg_b = (const float*)d_in[20];
    const float* ln1_g = (const float*)d_in[21]; const float* ln1_b = (const float*)d_in[22];
    const float* ln2_g = (const float*)d_in[23]; const float* ln2_b = (const float*)d_in[24];
    const float* cn_dw_w = (const float*)d_in[25]; const float* cn_dw_b = (const float*)d_in[26];
    const float* cn_ln_g = (const float*)d_in[27]; const float* cn_ln_b = (const float*)d_in[28];
    const float* cn_w1 = (const float*)d_in[29]; const float* cn_b1 = (const float*)d_in[30];
    const float* cn_w2 = (const float*)d_in[31]; const float* cn_b2 = (const float*)d_in[32];
    const float* cn_scale = (const float*)d_in[33]; const float* cn_alphas = (const float*)d_in[34];
    float* out = (float*)d_out;

    const size_t S = (size_t)BATCH * NTOK * CDIM;  // 6291456
    float* A0 = (float*)d_ws;
    float* A1 = A0 + S;
    short* Xb  = (short*)(A1 + S);
    short* QKV = Xb + S;            // 3*S bf16 (q | k | v)
    short* Ob  = QKV + 3 * S;
    short* Hb  = Ob + S;            // 2*S bf16
    short* Wqkv1 = Hb + 2 * S;
    short* Wqkv2 = Wqkv1 + 2304 * 768;
    short* WoT1  = Wqkv2 + 2304 * 768;
    short* WoT2  = WoT1 + 768 * 768;
    short* W1T   = WoT2 + 768 * 768;
    short* W2T   = W1T + (size_t)3072 * 768;
    float* bqkv1 = (float*)(W2T + (size_t)768 * 3072);
    float* bqkv2 = bqkv1 + 2304;
    // MLP-time aliases (QKV/Ob/Hb regions are dead by then):
    float* yF    = (float*)QKV;     // 8192x768 fp32 = first 2S shorts of QKV
    short* Hfull = QKV + 2 * S;     // 8192x3072 bf16 = 4S shorts (rest of QKV + Ob + Hb)

    dim3 tb(32, 8);
    dim3 dwgrid(8, 12, 8);

    // ---- weight prep (per-launch; ~30 us total) ----
    k_packqkv<<<dim3(12, 72), 256, 0, stream>>>(wq1, wk1, wv1, wq2, wk2, wv2, Wqkv1, Wqkv2);
    k_wtrans<<<dim3(24, 24), tb, 0, stream>>>(wo1, WoT1, 768, 768);
    k_wtrans<<<dim3(24, 24), tb, 0, stream>>>(wo2, WoT2, 768, 768);
    k_wtrans<<<dim3(96, 24), tb, 0, stream>>>(cn_w1, W1T, 768, 3072);
    k_wtrans<<<dim3(24, 96), tb, 0, stream>>>(cn_w2, W2T, 3072, 768);
    k_packbias<<<18, 256, 0, stream>>>(bq1, bk1, bv1, bq2, bk2, bv2, bqkv1, bqkv2);

    // ---- x = transpose(decoder), fp32 + bf16 ----
    k_transpose_in<<<dim3(32, 24, 8), tb, 0, stream>>>(dec, A0, Xb);

    // ---- block 1 ----
    k_gemm_mfma<GM_QKV, 128><<<dim3(64, 18), 256, 0, stream>>>(
        Xb, Wqkv1, bqkv1, nullptr, nullptr, nullptr, QKV, 8192, 2304, 768);
    k_attn_mfma<<<dim3(8, 12, 8), 256, 0, stream>>>(QKV, QKV + S, QKV + 2 * S, Ob);
    k_gemm_mfma<GM_PROJ, 64><<<dim3(64, 12), 256, 0, stream>>>(
        Ob, WoT1, bo1, A0, alphas1, A1, nullptr, 8192, 768, 768);
    k_dwconv_t<3><<<dwgrid, 256, 0, stream>>>(A1, peg_w, peg_b, A0);
    k_ln<<<8192, 256, 0, stream>>>(A0, ln1_g, ln1_b, A1, Xb);

    // ---- block 2 ----
    k_gemm_mfma<GM_QKV, 128><<<dim3(64, 18), 256, 0, stream>>>(
        Xb, Wqkv2, bqkv2, nullptr, nullptr, nullptr, QKV, 8192, 2304, 768);
    k_attn_mfma<<<dim3(8, 12, 8), 256, 0, stream>>>(QKV, QKV + S, QKV + 2 * S, Ob);
    k_gemm_mfma<GM_PROJ, 64><<<dim3(64, 12), 256, 0, stream>>>(
        Ob, WoT2, bo2, A1, alphas2, A0, nullptr, 8192, 768, 768);
    k_ln<<<8192, 256, 0, stream>>>(A0, ln2_g, ln2_b, A1, nullptr);  // A1 = xln2 (kept)

    // ---- CNBlock head ----
    k_dwconv_t<7><<<dwgrid, 256, 0, stream>>>(A1, cn_dw_w, cn_dw_b, A0);
    k_ln<<<8192, 256, 0, stream>>>(A0, cn_ln_g, cn_ln_b, nullptr, Xb);
    // MLP, full M=8192 (Hfull aliases dead QKV-tail/Ob/Hb; yF aliases QKV head)
    k_gemm_mfma<GM_GELU, 128><<<dim3(64, 24), 256, 0, stream>>>(
        Xb, W1T, cn_b1, nullptr, nullptr, nullptr, Hfull, 8192, 3072, 768);
    k_gemm_mfma<GM_PLAIN, 64><<<dim3(64, 12), 256, 0, stream>>>(
        Hfull, W2T, cn_b2, nullptr, nullptr, yF, nullptr, 8192, 768, 3072);
    // ---- out = cn_scale*y + cn_alphas*xln2, transposed to [B,C,H,W] ----
    k_final<<<dim3(32, 24, 8), tb, 0, stream>>>(yF, A1, cn_scale, cn_alphas, out);
}

// Round 7
// 655.369 us; speedup vs baseline: 7.3584x; 1.0459x over previous
//
#include <hip/hip_runtime.h>
#include <math.h>

#define BATCH 8
#define CDIM 768
#define NTOK 1024
#define NH 12
#define HDIM 64

typedef __attribute__((ext_vector_type(8))) short bf16x8;
typedef __attribute__((ext_vector_type(4))) float f32x4;

__device__ inline short f2bf(float f) {
    union { float f; unsigned u; } v; v.f = f;
    unsigned r = (v.u + 0x7FFF + ((v.u >> 16) & 1)) >> 16;
    return (short)r;
}

// async global->LDS DMA, 16 B per lane; lptr must be the WAVE-uniform base,
// lane l writes lptr + l*16 bytes (m97 pattern).
__device__ inline void async_copy16(const short* g, short* l) {
    __builtin_amdgcn_global_load_lds(
        (const __attribute__((address_space(1))) void*)g,
        (__attribute__((address_space(3))) void*)l, 16, 0, 0);
}

// ---------------- transpose [B,C,N] -> [B,N,C], fp32 + bf16 mirror ----------------
__global__ void k_transpose_in(const float* __restrict__ dec, float* __restrict__ x,
                               short* __restrict__ xb) {
    __shared__ float tile[32][33];
    int b = blockIdx.z;
    int n0 = blockIdx.x * 32;
    int c0 = blockIdx.y * 32;
    int tx = threadIdx.x, ty = threadIdx.y;
#pragma unroll
    for (int r = 0; r < 4; ++r) {
        int c = c0 + ty + r * 8;
        tile[ty + r * 8][tx] = dec[((size_t)b * CDIM + c) * NTOK + n0 + tx];
    }
    __syncthreads();
#pragma unroll
    for (int r = 0; r < 4; ++r) {
        int n = n0 + ty + r * 8;
        float val = tile[tx][ty + r * 8];
        size_t idx = ((size_t)b * NTOK + n) * CDIM + c0 + tx;
        x[idx] = val;
        xb[idx] = f2bf(val);
    }
}

// ---------------- weight transpose fp32 [R,C] -> bf16 [C,R] ----------------
__global__ void k_wtrans(const float* __restrict__ src, short* __restrict__ dst,
                         int R, int C) {
    __shared__ float tile[32][33];
    int c0 = blockIdx.x * 32, r0 = blockIdx.y * 32;
    int tx = threadIdx.x, ty = threadIdx.y;
#pragma unroll
    for (int p = 0; p < 4; ++p)
        tile[ty + p * 8][tx] = src[(size_t)(r0 + ty + p * 8) * C + c0 + tx];
    __syncthreads();
#pragma unroll
    for (int p = 0; p < 4; ++p)
        dst[(size_t)(c0 + ty + p * 8) * R + r0 + tx] = f2bf(tile[tx][ty + p * 8]);
}

// ---------------- pack per-head qkv weights -> [2304,768] bf16 (n = sect*768+h*64+d) ----
__global__ __launch_bounds__(256) void k_packqkv(
    const float* __restrict__ wq1, const float* __restrict__ wk1, const float* __restrict__ wv1,
    const float* __restrict__ wq2, const float* __restrict__ wk2, const float* __restrict__ wv2,
    short* __restrict__ dst1, short* __restrict__ dst2) {
    __shared__ float tile[64][65];
    int z = blockIdx.y;                 // 0..71
    int set = z / 36, rem = z % 36, sect = rem / 12, h = rem % 12;
    const float* srcs[6] = {wq1, wk1, wv1, wq2, wk2, wv2};
    const float* src = srcs[set * 3 + sect] + (size_t)h * 768 * 64;
    short* dst = (set ? dst2 : dst1) + ((size_t)sect * 768 + h * 64) * 768;
    int k0 = blockIdx.x * 64;
    int t = threadIdx.x;
#pragma unroll
    for (int p = 0; p < 16; ++p) {
        int gid = t + p * 256;
        int r = gid >> 6, c = gid & 63;
        tile[r][c] = src[(size_t)(k0 + r) * 64 + c];
    }
    __syncthreads();
#pragma unroll
    for (int p = 0; p < 16; ++p) {
        int gid = t + p * 256;
        int d = gid >> 6, kk = gid & 63;
        dst[(size_t)d * 768 + k0 + kk] = f2bf(tile[kk][d]);
    }
}

__global__ void k_packbias(const float* __restrict__ bq1, const float* __restrict__ bk1,
                           const float* __restrict__ bv1, const float* __restrict__ bq2,
                           const float* __restrict__ bk2, const float* __restrict__ bv2,
                           float* __restrict__ d1, float* __restrict__ d2) {
    int tid = blockIdx.x * 256 + threadIdx.x;
    if (tid >= 4608) return;
    int set = tid / 2304, n = tid % 2304;
    int sect = n / 768, rem = n % 768;
    const float* srcs[6] = {bq1, bk1, bv1, bq2, bk2, bv2};
    float v = srcs[set * 3 + sect][rem];
    (set ? d2 : d1)[n] = v;
}

// ---------------- generic bf16 MFMA GEMM, 128xBN tile, 2x BK32 per barrier ----------------
// A [M,K] bf16 row-major; Bt [N,K] bf16 row-major (i.e. B transposed)
// Two side-by-side 128x32 LDS tiles per operand (preserves the 64B-row-stride
// bank layout = conflict-free minimum); one barrier pair per 64 K. DMA staging.
#define GM_PLAIN 0
#define GM_PROJ  1
#define GM_GELU  2
#define GM_QKV   3
#define QKVSEC ((size_t)BATCH * NH * NTOK * HDIM)  // 6291456

template<int MODE, int BN>
__global__ __launch_bounds__(256) void k_gemm_mfma(
    const short* __restrict__ A, const short* __restrict__ Bt,
    const float* __restrict__ bias, const float* __restrict__ resid,
    const float* __restrict__ rscale, float* __restrict__ outF,
    short* __restrict__ outB, int M, int N, int K) {
    constexpr int NT = BN / 32;   // 16-col tiles per wave
    constexpr int BP = BN / 64;   // B staging passes per 32-chunk
    __shared__ short As[2 * 128 * 32];
    __shared__ short Bs[2 * BN * 32];
    int t = threadIdx.x;
    int w = t >> 6, lane = t & 63, l15 = lane & 15, quad = lane >> 4;
    int r0 = blockIdx.x * 128, n0 = blockIdx.y * BN;
    int wr = (w >> 1) * 64, wc = (w & 1) * (BN / 2);
    f32x4 acc[4][NT];
#pragma unroll
    for (int i = 0; i < 4; ++i)
#pragma unroll
        for (int j = 0; j < NT; ++j) acc[i][j] = (f32x4){0.f, 0.f, 0.f, 0.f};
    int sr = t >> 2, sc = (t & 3) * 8;
    const short* Ag = A + (size_t)(r0 + sr) * K + sc;
    const short* Bg = Bt + (size_t)(n0 + sr) * K + sc;
    short* AsW = As + w * 512;   // wave-uniform base: lane l -> + l*8 shorts (16 B)
    short* BsW = Bs + w * 512;
    for (int k0 = 0; k0 < K; k0 += 64) {
        __syncthreads();
#pragma unroll
        for (int c = 0; c < 2; ++c) {
#pragma unroll
            for (int p = 0; p < 2; ++p)
                async_copy16(Ag + k0 + c * 32 + (size_t)p * 64 * K,
                             AsW + c * 4096 + p * 2048);
#pragma unroll
            for (int p = 0; p < BP; ++p)
                async_copy16(Bg + k0 + c * 32 + (size_t)p * 64 * K,
                             BsW + c * (BN * 32) + p * 2048);
        }
        __syncthreads();   // drains vmcnt(0): DMA complete for all waves
#pragma unroll
        for (int c = 0; c < 2; ++c) {
            bf16x8 af[4], bf[NT];
#pragma unroll
            for (int i = 0; i < 4; ++i)
                af[i] = *(const bf16x8*)&As[c * 4096 + (wr + i * 16 + l15) * 32 + quad * 8];
#pragma unroll
            for (int j = 0; j < NT; ++j)
                bf[j] = *(const bf16x8*)&Bs[c * (BN * 32) + (wc + j * 16 + l15) * 32 + quad * 8];
#pragma unroll
            for (int i = 0; i < 4; ++i)
#pragma unroll
                for (int j = 0; j < NT; ++j)
                    acc[i][j] = __builtin_amdgcn_mfma_f32_16x16x32_bf16(af[i], bf[j], acc[i][j], 0, 0, 0);
        }
    }
#pragma unroll
    for (int i = 0; i < 4; ++i)
#pragma unroll
        for (int j = 0; j < NT; ++j)
#pragma unroll
            for (int rr = 0; rr < 4; ++rr) {
                int row = r0 + wr + i * 16 + quad * 4 + rr;
                int col = n0 + wc + j * 16 + l15;
                float val = acc[i][j][rr] + bias[col];
                if (MODE == GM_PROJ) {
                    val += rscale[col] * resid[(size_t)row * N + col];
                    outF[(size_t)row * N + col] = val;
                } else if (MODE == GM_GELU) {
                    // tanh-form GELU via hw exp2/rcp: x*sigmoid(1.595769*(x+0.044715x^3))
                    float u = val * (1.0f + 0.044715f * val * val);
                    float zz = __builtin_amdgcn_rcpf(
                        1.0f + __builtin_amdgcn_exp2f(-2.3022082f * u));
                    outB[(size_t)row * N + col] = f2bf(val * zz);
                } else if (MODE == GM_PLAIN) {
                    outF[(size_t)row * N + col] = val;
                } else {  // GM_QKV: scatter into q/k/v [B,H,N,64]
                    int sect = col / 768, rem = col - sect * 768;
                    int hh = rem >> 6, d = rem & 63;
                    int bb = row >> 10, tok = row & 1023;
                    outB[(size_t)sect * QKVSEC +
                         (((size_t)bb * NH + hh) * NTOK + tok) * HDIM + d] = f2bf(val);
                }
            }
}

// ---------------- MFMA sigmoid attention ----------------
// per (b,h): O = sigmoid(QK^T/8) V ; q/k/v [B,H,N,64] bf16; O -> [B,N,C] bf16
__global__ __launch_bounds__(256) void k_attn_mfma(
    const short* __restrict__ q, const short* __restrict__ k,
    const short* __restrict__ v, short* __restrict__ o) {
    __shared__ short Ks[64][72];
    __shared__ short Vt[64][72];
    __shared__ short Ps[128][72];
    int b = blockIdx.z, h = blockIdx.y;
    int q0 = blockIdx.x * 128;
    int t = threadIdx.x;
    int w = t >> 6, lane = t & 63, l15 = lane & 15, quad = lane >> 4;
    size_t base = ((size_t)(b * NH + h)) * NTOK * HDIM;
    const short* qp = q + base;
    const short* kp = k + base;
    const short* vp = v + base;
    bf16x8 qf[2][2];
#pragma unroll
    for (int mt = 0; mt < 2; ++mt)
#pragma unroll
        for (int kc = 0; kc < 2; ++kc)
            qf[mt][kc] = *(const bf16x8*)&qp[(size_t)(q0 + w * 32 + mt * 16 + l15) * HDIM + kc * 32 + quad * 8];
    f32x4 oacc[2][4];
#pragma unroll
    for (int mt = 0; mt < 2; ++mt)
#pragma unroll
        for (int dt = 0; dt < 4; ++dt) oacc[mt][dt] = (f32x4){0.f, 0.f, 0.f, 0.f};
    for (int kt = 0; kt < 16; ++kt) {
        __syncthreads();
#pragma unroll
        for (int p = 0; p < 2; ++p) {
            int gid = t + p * 256;
            int r = gid >> 3, c8 = (gid & 7) * 8;
            *(bf16x8*)&Ks[r][c8] = *(const bf16x8*)&kp[(size_t)(kt * 64 + r) * HDIM + c8];
        }
#pragma unroll
        for (int p = 0; p < 2; ++p) {
            int tok = t & 63, d0 = (t >> 6) * 8 + p * 32;
            bf16x8 vv = *(const bf16x8*)&vp[(size_t)(kt * 64 + tok) * HDIM + d0];
#pragma unroll
            for (int j = 0; j < 8; ++j) Vt[d0 + j][tok] = vv[j];
        }
        __syncthreads();
        // S = Q K^T for this wave's 32 q-rows x 64 keys
        f32x4 sacc[2][4];
#pragma unroll
        for (int mt = 0; mt < 2; ++mt)
#pragma unroll
            for (int nt = 0; nt < 4; ++nt) sacc[mt][nt] = (f32x4){0.f, 0.f, 0.f, 0.f};
#pragma unroll
        for (int nt = 0; nt < 4; ++nt) {
            bf16x8 kf0 = *(const bf16x8*)&Ks[nt * 16 + l15][quad * 8];
            bf16x8 kf1 = *(const bf16x8*)&Ks[nt * 16 + l15][32 + quad * 8];
#pragma unroll
            for (int mt = 0; mt < 2; ++mt) {
                sacc[mt][nt] = __builtin_amdgcn_mfma_f32_16x16x32_bf16(qf[mt][0], kf0, sacc[mt][nt], 0, 0, 0);
                sacc[mt][nt] = __builtin_amdgcn_mfma_f32_16x16x32_bf16(qf[mt][1], kf1, sacc[mt][nt], 0, 0, 0);
            }
        }
        // sigmoid -> P (bf16, LDS round-trip to A-operand layout); rows wave-private
#pragma unroll
        for (int mt = 0; mt < 2; ++mt)
#pragma unroll
            for (int nt = 0; nt < 4; ++nt)
#pragma unroll
                for (int rr = 0; rr < 4; ++rr) {
                    float s = sacc[mt][nt][rr];
                    float z = __builtin_amdgcn_rcpf(
                        1.0f + __builtin_amdgcn_exp2f(s * -0.18033688011112042f));
                    Ps[w * 32 + mt * 16 + quad * 4 + rr][nt * 16 + l15] = f2bf(z);
                }
        __syncthreads();
        // O += P V
        bf16x8 vfr[2][4];
#pragma unroll
        for (int kc = 0; kc < 2; ++kc)
#pragma unroll
            for (int dt = 0; dt < 4; ++dt)
                vfr[kc][dt] = *(const bf16x8*)&Vt[dt * 16 + l15][kc * 32 + quad * 8];
#pragma unroll
        for (int mt = 0; mt < 2; ++mt)
#pragma unroll
            for (int kc = 0; kc < 2; ++kc) {
                bf16x8 pf = *(const bf16x8*)&Ps[w * 32 + mt * 16 + l15][kc * 32 + quad * 8];
#pragma unroll
                for (int dt = 0; dt < 4; ++dt)
                    oacc[mt][dt] = __builtin_amdgcn_mfma_f32_16x16x32_bf16(pf, vfr[kc][dt], oacc[mt][dt], 0, 0, 0);
            }
    }
#pragma unroll
    for (int mt = 0; mt < 2; ++mt)
#pragma unroll
        for (int dt = 0; dt < 4; ++dt)
#pragma unroll
            for (int rr = 0; rr < 4; ++rr) {
                int tok = q0 + w * 32 + mt * 16 + quad * 4 + rr;
                int c = h * 64 + dt * 16 + l15;
                o[((size_t)b * NTOK + tok) * CDIM + c] = f2bf(oacc[mt][dt][rr]);
            }
}

// ---------------- depthwise conv, register sliding window (fp32) ----------------
template<int K>
__global__ __launch_bounds__(256) void k_dwconv_t(
    const float* __restrict__ in, const float* __restrict__ w,
    const float* __restrict__ bias, float* __restrict__ out) {
    constexpr int PAD = K / 2;
    constexpr int KK = K * K;
    int t = threadIdx.x;
    int c = blockIdx.y * 64 + (t & 63);
    int j = blockIdx.x * 4 + (t >> 6);
    int b = blockIdx.z;
    float wr[KK];
#pragma unroll
    for (int qq = 0; qq < KK; ++qq) wr[qq] = w[(size_t)c * KK + qq];
    float bsv = bias[c];
    const float* base = in + (size_t)b * NTOK * CDIM + c;
    float win[K][K];
#pragma unroll
    for (int s = 1; s < K; ++s) {
        int ii = s - 1 - PAD;
#pragma unroll
        for (int qq = 0; qq < K; ++qq) {
            int jj = j - PAD + qq;
            win[s][qq] = (ii >= 0 && jj >= 0 && jj < 32)
                         ? base[(size_t)(ii * 32 + jj) * CDIM] : 0.0f;
        }
    }
#pragma unroll
    for (int i = 0; i < 32; ++i) {
#pragma unroll
        for (int r = 0; r < K - 1; ++r)
#pragma unroll
            for (int qq = 0; qq < K; ++qq) win[r][qq] = win[r + 1][qq];
        int ii = i + PAD;
#pragma unroll
        for (int qq = 0; qq < K; ++qq) {
            int jj = j - PAD + qq;
            win[K - 1][qq] = (ii < 32 && jj >= 0 && jj < 32)
                             ? base[(size_t)(ii * 32 + jj) * CDIM] : 0.0f;
        }
        float acc = bsv;
#pragma unroll
        for (int r = 0; r < K; ++r)
#pragma unroll
            for (int qq = 0; qq < K; ++qq)
                acc = fmaf(win[r][qq], wr[r * K + qq], acc);
        out[((size_t)b * NTOK + i * 32 + j) * CDIM + c] = acc;
    }
}

// ---------------- layernorm over C=768, nullable fp32/bf16 outputs ----------------
__global__ __launch_bounds__(256) void k_ln(
    const float* __restrict__ in, const float* __restrict__ g,
    const float* __restrict__ b, float* __restrict__ outF, short* __restrict__ outB) {
    int row = blockIdx.x;
    const float* xr = in + (size_t)row * CDIM;
    int t = threadIdx.x;
    float x0 = xr[t], x1 = xr[t + 256], x2 = xr[t + 512];
    float s = x0 + x1 + x2;
    float sq = x0 * x0 + x1 * x1 + x2 * x2;
#pragma unroll
    for (int off = 32; off > 0; off >>= 1) {
        s += __shfl_down(s, off);
        sq += __shfl_down(sq, off);
    }
    __shared__ float ws[4], wq2[4];
    int wid = t >> 6, lane = t & 63;
    if (lane == 0) { ws[wid] = s; wq2[wid] = sq; }
    __syncthreads();
    if (t == 0) {
        float S = ws[0] + ws[1] + ws[2] + ws[3];
        float Q = wq2[0] + wq2[1] + wq2[2] + wq2[3];
        float m = S * (1.0f / CDIM);
        float var = Q * (1.0f / CDIM) - m * m;
        ws[0] = m;
        wq2[0] = rsqrtf(var + 1e-5f);
    }
    __syncthreads();
    float m = ws[0], inv = wq2[0];
    float y0 = (x0 - m) * inv * g[t] + b[t];
    float y1 = (x1 - m) * inv * g[t + 256] + b[t + 256];
    float y2 = (x2 - m) * inv * g[t + 512] + b[t + 512];
    if (outF) {
        float* orow = outF + (size_t)row * CDIM;
        orow[t] = y0; orow[t + 256] = y1; orow[t + 512] = y2;
    }
    if (outB) {
        short* orow = outB + (size_t)row * CDIM;
        orow[t] = f2bf(y0); orow[t + 256] = f2bf(y1); orow[t + 512] = f2bf(y2);
    }
}

// ---------------- final combine + transpose back to [B,C,N] ----------------
__global__ void k_final(const float* __restrict__ y, const float* __restrict__ xln,
                        const float* __restrict__ scale, const float* __restrict__ alph,
                        float* __restrict__ out) {
    __shared__ float tile[32][33];
    int b = blockIdx.z, n0 = blockIdx.x * 32, c0 = blockIdx.y * 32;
    int tx = threadIdx.x, ty = threadIdx.y;
#pragma unroll
    for (int r = 0; r < 4; ++r) {
        int n = n0 + ty + r * 8, c = c0 + tx;
        size_t idx = ((size_t)b * NTOK + n) * CDIM + c;
        tile[tx][ty + r * 8] = scale[c] * y[idx] + alph[c] * xln[idx];
    }
    __syncthreads();
#pragma unroll
    for (int r = 0; r < 4; ++r) {
        int c = c0 + ty + r * 8;
        out[((size_t)b * CDIM + c) * NTOK + n0 + tx] = tile[ty + r * 8][tx];
    }
}

extern "C" void kernel_launch(void* const* d_in, const int* in_sizes, int n_in,
                              void* d_out, int out_size, void* d_ws, size_t ws_size,
                              hipStream_t stream) {
    const float* dec = (const float*)d_in[0];
    const float* wq1 = (const float*)d_in[1]; const float* bq1 = (const float*)d_in[2];
    const float* wk1 = (const float*)d_in[3]; const float* bk1 = (const float*)d_in[4];
    const float* wv1 = (const float*)d_in[5]; const float* bv1 = (const float*)d_in[6];
    const float* wo1 = (const float*)d_in[7]; const float* bo1 = (const float*)d_in[8];
    const float* wq2 = (const float*)d_in[9]; const float* bq2 = (const float*)d_in[10];
    const float* wk2 = (const float*)d_in[11]; const float* bk2 = (const float*)d_in[12];
    const float* wv2 = (const float*)d_in[13]; const float* bv2 = (const float*)d_in[14];
    const float* wo2 = (const float*)d_in[15]; const float* bo2 = (const float*)d_in[16];
    const float* alphas1 = (const float*)d_in[17];
    const float* alphas2 = (const float*)d_in[18];
    const float* peg_w = (const float*)d_in[19]; const float* peg_b = (const float*)d_in[20];
    const float* ln1_g = (const float*)d_in[21]; const float* ln1_b = (const float*)d_in[22];
    const float* ln2_g = (const float*)d_in[23]; const float* ln2_b = (const float*)d_in[24];
    const float* cn_dw_w = (const float*)d_in[25]; const float* cn_dw_b = (const float*)d_in[26];
    const float* cn_ln_g = (const float*)d_in[27]; const float* cn_ln_b = (const float*)d_in[28];
    const float* cn_w1 = (const float*)d_in[29]; const float* cn_b1 = (const float*)d_in[30];
    const float* cn_w2 = (const float*)d_in[31]; const float* cn_b2 = (const float*)d_in[32];
    const float* cn_scale = (const float*)d_in[33]; const float* cn_alphas = (const float*)d_in[34];
    float* out = (float*)d_out;

    const size_t S = (size_t)BATCH * NTOK * CDIM;  // 6291456
    float* A0 = (float*)d_ws;
    float* A1 = A0 + S;
    short* Xb  = (short*)(A1 + S);
    short* QKV = Xb + S;            // 3*S bf16 (q | k | v)
    short* Ob  = QKV + 3 * S;
    short* Hb  = Ob + S;            // 2*S bf16
    short* Wqkv1 = Hb + 2 * S;
    short* Wqkv2 = Wqkv1 + 2304 * 768;
    short* WoT1  = Wqkv2 + 2304 * 768;
    short* WoT2  = WoT1 + 768 * 768;
    short* W1T   = WoT2 + 768 * 768;
    short* W2T   = W1T + (size_t)3072 * 768;
    float* bqkv1 = (float*)(W2T + (size_t)768 * 3072);
    float* bqkv2 = bqkv1 + 2304;
    // MLP-time aliases (QKV/Ob/Hb regions are dead by then):
    float* yF    = (float*)QKV;     // 8192x768 fp32 = first 2S shorts of QKV
    short* Hfull = QKV + 2 * S;     // 8192x3072 bf16 = 4S shorts (rest of QKV + Ob + Hb)

    dim3 tb(32, 8);
    dim3 dwgrid(8, 12, 8);

    // ---- weight prep (per-launch; ~30 us total) ----
    k_packqkv<<<dim3(12, 72), 256, 0, stream>>>(wq1, wk1, wv1, wq2, wk2, wv2, Wqkv1, Wqkv2);
    k_wtrans<<<dim3(24, 24), tb, 0, stream>>>(wo1, WoT1, 768, 768);
    k_wtrans<<<dim3(24, 24), tb, 0, stream>>>(wo2, WoT2, 768, 768);
    k_wtrans<<<dim3(96, 24), tb, 0, stream>>>(cn_w1, W1T, 768, 3072);
    k_wtrans<<<dim3(24, 96), tb, 0, stream>>>(cn_w2, W2T, 3072, 768);
    k_packbias<<<18, 256, 0, stream>>>(bq1, bk1, bv1, bq2, bk2, bv2, bqkv1, bqkv2);

    // ---- x = transpose(decoder), fp32 + bf16 ----
    k_transpose_in<<<dim3(32, 24, 8), tb, 0, stream>>>(dec, A0, Xb);

    // ---- block 1 ----
    k_gemm_mfma<GM_QKV, 128><<<dim3(64, 18), 256, 0, stream>>>(
        Xb, Wqkv1, bqkv1, nullptr, nullptr, nullptr, QKV, 8192, 2304, 768);
    k_attn_mfma<<<dim3(8, 12, 8), 256, 0, stream>>>(QKV, QKV + S, QKV + 2 * S, Ob);
    k_gemm_mfma<GM_PROJ, 64><<<dim3(64, 12), 256, 0, stream>>>(
        Ob, WoT1, bo1, A0, alphas1, A1, nullptr, 8192, 768, 768);
    k_dwconv_t<3><<<dwgrid, 256, 0, stream>>>(A1, peg_w, peg_b, A0);
    k_ln<<<8192, 256, 0, stream>>>(A0, ln1_g, ln1_b, A1, Xb);

    // ---- block 2 ----
    k_gemm_mfma<GM_QKV, 128><<<dim3(64, 18), 256, 0, stream>>>(
        Xb, Wqkv2, bqkv2, nullptr, nullptr, nullptr, QKV, 8192, 2304, 768);
    k_attn_mfma<<<dim3(8, 12, 8), 256, 0, stream>>>(QKV, QKV + S, QKV + 2 * S, Ob);
    k_gemm_mfma<GM_PROJ, 64><<<dim3(64, 12), 256, 0, stream>>>(
        Ob, WoT2, bo2, A1, alphas2, A0, nullptr, 8192, 768, 768);
    k_ln<<<8192, 256, 0, stream>>>(A0, ln2_g, ln2_b, A1, nullptr);  // A1 = xln2 (kept)

    // ---- CNBlock head ----
    k_dwconv_t<7><<<dwgrid, 256, 0, stream>>>(A1, cn_dw_w, cn_dw_b, A0);
    k_ln<<<8192, 256, 0, stream>>>(A0, cn_ln_g, cn_ln_b, nullptr, Xb);
    // MLP, full M=8192 (Hfull aliases dead QKV-tail/Ob/Hb; yF aliases QKV head)
    k_gemm_mfma<GM_GELU, 128><<<dim3(64, 24), 256, 0, stream>>>(
        Xb, W1T, cn_b1, nullptr, nullptr, nullptr, Hfull, 8192, 3072, 768);
    k_gemm_mfma<GM_PLAIN, 64><<<dim3(64, 12), 256, 0, stream>>>(
        Hfull, W2T, cn_b2, nullptr, nullptr, yF, nullptr, 8192, 768, 3072);
    // ---- out = cn_scale*y + cn_alphas*xln2, transposed to [B,C,H,W] ----
    k_final<<<dim3(32, 24, 8), tb, 0, stream>>>(yF, A1, cn_scale, cn_alphas, out);
}